// Round 6
// baseline (2481.173 us; speedup 1.0000x reference)
//
#include <hip/hip_runtime.h>
#include <hip/hip_bf16.h>

// Problem constants (fixed by reference)
#define N_NODES 50000
#define N_EDGES 500000
#define N_GRAPHS 512

// ===========================================================================
// Strategy (R6): scatter-free via CSR gather, sized to fit workspace.
// - Edge kernel: e1 (fp32, LDS-only) -> e2 (bf16, materialized, 128 MB);
//   per-graph fp32 atomic sums. NO node-scatter atomics.
// - CSR build (count/scan/fill): receiver- and sender-sorted edge id lists.
// - Node kernel: per (node,half) WAVE task gathers incident edges; e1 rows
//   are RECOMPUTED from raw e (16 KFLOP/visit) with We1 staged in LDS and
//   __shfl broadcast of e-row values; e2 rows gathered from e2bf. Block-1
//   aggregation is exact fp32. Workspace ~136 MB (R4's 155 MB fit).
// ===========================================================================

// --------------------------- CSR build kernels -----------------------------
__global__ __launch_bounds__(256) void count_kernel(
    const int* __restrict__ recv, const int* __restrict__ send,
    int* __restrict__ rc, int* __restrict__ sc)
{
    const int i = blockIdx.x * 256 + threadIdx.x;
    if (i < N_EDGES) {
        atomicAdd(&rc[recv[i]], 1);
        atomicAdd(&sc[send[i]], 1);
    }
}

#define SCAN_B 512
#define SCAN_NB ((N_NODES + SCAN_B - 1) / SCAN_B)  // 98

__global__ __launch_bounds__(SCAN_B) void scan1_kernel(
    const int* __restrict__ rc, const int* __restrict__ sc,
    int* __restrict__ rps, int* __restrict__ sps,
    int* __restrict__ rbt, int* __restrict__ sbt)
{
    __shared__ int sm[SCAN_B];
    const int tid = threadIdx.x;
    const int gid = blockIdx.x * SCAN_B + tid;
    const int* cnt = blockIdx.y ? sc : rc;
    int* ps = blockIdx.y ? sps : rps;
    int* bt = blockIdx.y ? sbt : rbt;
    const int v = (gid < N_NODES) ? cnt[gid] : 0;
    sm[tid] = v;
    __syncthreads();
    for (int off = 1; off < SCAN_B; off <<= 1) {
        const int t2 = (tid >= off) ? sm[tid - off] : 0;
        __syncthreads();
        sm[tid] += t2;
        __syncthreads();
    }
    if (gid < N_NODES) ps[gid] = sm[tid] - v;   // exclusive within block
    if (tid == SCAN_B - 1) bt[blockIdx.x] = sm[tid];
}

__global__ void scan2_kernel(int* __restrict__ rbt, int* __restrict__ sbt) {
    if (threadIdx.x == 0) {
        int a = 0;
        for (int i = 0; i < SCAN_NB; i++) { const int t = rbt[i]; rbt[i] = a; a += t; }
    }
    if (threadIdx.x == 1) {
        int a = 0;
        for (int i = 0; i < SCAN_NB; i++) { const int t = sbt[i]; sbt[i] = a; a += t; }
    }
}

__global__ __launch_bounds__(256) void scan3_kernel(
    const int* __restrict__ rps, const int* __restrict__ sps,
    const int* __restrict__ rbt, const int* __restrict__ sbt,
    int* __restrict__ r_start, int* __restrict__ s_start,
    int* __restrict__ r_cur, int* __restrict__ s_cur)
{
    const int i = blockIdx.x * 256 + threadIdx.x;
    if (i < N_NODES) {
        const int r = rps[i] + rbt[i >> 9];
        const int s = sps[i] + sbt[i >> 9];
        r_start[i] = r; r_cur[i] = r;
        s_start[i] = s; s_cur[i] = s;
    }
    if (i == 0) { r_start[N_NODES] = N_EDGES; s_start[N_NODES] = N_EDGES; }
}

__global__ __launch_bounds__(256) void fill_kernel(
    const int* __restrict__ recv, const int* __restrict__ send,
    int* __restrict__ r_cur, int* __restrict__ s_cur,
    int* __restrict__ r_edges, int* __restrict__ s_edges)
{
    const int i = blockIdx.x * 256 + threadIdx.x;
    if (i < N_EDGES) {
        r_edges[atomicAdd(&r_cur[recv[i]], 1)] = i;
        s_edges[atomicAdd(&s_cur[send[i]], 1)] = i;
    }
}

// ---------------------------------------------------------------------------
// Edge kernel: e1=relu(e@We1+be1) [256] in LDS only; e2=relu(e1@We2+be2)
// [128] written as bf16 rows (streaming stores); per-graph fp32 atomic sums.
// ---------------------------------------------------------------------------
#define EPB 16  // edges per block; 500000 % 16 == 0

__global__ __launch_bounds__(256) void edge_kernel(
    const float* __restrict__ e,          // [E,32]
    const int* __restrict__ edge_graph,   // sorted
    const float* __restrict__ We1, const float* __restrict__ be1,   // [32,256],[256]
    const float* __restrict__ We2, const float* __restrict__ be2,   // [256,128],[128]
    __hip_bfloat162* __restrict__ e2bf,   // [E,64]  (bf16 x2 = 128 ch)
    float* __restrict__ ge1, float* __restrict__ ge2, float* __restrict__ gecnt)
{
    __shared__ float eL[EPB * 32];     // 2 KB
    __shared__ float e1L[EPB * 256];   // 16 KB
    __shared__ float e2L[EPB * 128];   // 8 KB
    __shared__ int gidx[EPB];

    const int t = threadIdx.x;
    const long e0 = (long)blockIdx.x * EPB;

    for (int i = t; i < EPB * 32; i += 256) eL[i] = e[e0 * 32 + i];
    if (t < EPB) gidx[t] = edge_graph[e0 + t];
    __syncthreads();

    // ---- e1 = relu(e @ We1 + be1). thread: 4 channels, 4 edges.
    {
        const int c0 = (t & 63) * 4;
        const int jb = (t >> 6) * 4;
        float4 acc[4];
        const float4 b4 = *(const float4*)&be1[c0];
        #pragma unroll
        for (int j = 0; j < 4; j++) acc[j] = b4;
        for (int k = 0; k < 32; k += 4) {
            float4 v[4];
            #pragma unroll
            for (int j = 0; j < 4; j++) v[j] = *(const float4*)&eL[(jb + j) * 32 + k];
            #pragma unroll
            for (int kk = 0; kk < 4; kk++) {
                const float4 w = *(const float4*)&We1[(size_t)(k + kk) * 256 + c0];
                #pragma unroll
                for (int j = 0; j < 4; j++) {
                    const float vv = ((const float*)&v[j])[kk];
                    acc[j].x = fmaf(vv, w.x, acc[j].x);
                    acc[j].y = fmaf(vv, w.y, acc[j].y);
                    acc[j].z = fmaf(vv, w.z, acc[j].z);
                    acc[j].w = fmaf(vv, w.w, acc[j].w);
                }
            }
        }
        #pragma unroll
        for (int j = 0; j < 4; j++) {
            float4 r;
            r.x = fmaxf(acc[j].x, 0.f); r.y = fmaxf(acc[j].y, 0.f);
            r.z = fmaxf(acc[j].z, 0.f); r.w = fmaxf(acc[j].w, 0.f);
            *(float4*)&e1L[(jb + j) * 256 + c0] = r;
        }
    }
    __syncthreads();

    // ---- e2 = relu(e1 @ We2 + be2). thread: 4 channels, 2 edges.
    {
        const int c0 = (t & 31) * 4;
        const int jb = (t >> 5) * 2;
        float4 acc[2];
        const float4 b4 = *(const float4*)&be2[c0];
        #pragma unroll
        for (int j = 0; j < 2; j++) acc[j] = b4;
        for (int k = 0; k < 256; k += 4) {
            float4 v[2];
            #pragma unroll
            for (int j = 0; j < 2; j++) v[j] = *(const float4*)&e1L[(jb + j) * 256 + k];
            #pragma unroll
            for (int kk = 0; kk < 4; kk++) {
                const float4 w = *(const float4*)&We2[(size_t)(k + kk) * 128 + c0];
                #pragma unroll
                for (int j = 0; j < 2; j++) {
                    const float vv = ((const float*)&v[j])[kk];
                    acc[j].x = fmaf(vv, w.x, acc[j].x);
                    acc[j].y = fmaf(vv, w.y, acc[j].y);
                    acc[j].z = fmaf(vv, w.z, acc[j].z);
                    acc[j].w = fmaf(vv, w.w, acc[j].w);
                }
            }
        }
        #pragma unroll
        for (int j = 0; j < 2; j++) {
            float4 r;
            r.x = fmaxf(acc[j].x, 0.f); r.y = fmaxf(acc[j].y, 0.f);
            r.z = fmaxf(acc[j].z, 0.f); r.w = fmaxf(acc[j].w, 0.f);
            *(float4*)&e2L[(jb + j) * 128 + c0] = r;
        }
    }
    __syncthreads();

    // ---- materialize e2 bf16 rows (coalesced streaming stores)
    for (int i = t; i < EPB * 64; i += 256) {
        const int ee = i >> 6, p = i & 63;
        const float2 v = *(const float2*)&e2L[ee * 128 + 2 * p];
        e2bf[(size_t)(e0 + ee) * 64 + p] = __float22bfloat162_rn(v);
    }

    // ---- per-graph sums (edge_graph sorted: usually one run per block), fp32
    if (gidx[0] == gidx[EPB - 1]) {
        const int g = gidx[0];
        float s = 0.f;
        #pragma unroll
        for (int j = 0; j < EPB; j++) s += e1L[j * 256 + t];
        atomicAdd(&ge1[(size_t)g * 256 + t], s);
        if (t < 128) {
            float s2 = 0.f;
            #pragma unroll
            for (int j = 0; j < EPB; j++) s2 += e2L[j * 128 + t];
            atomicAdd(&ge2[(size_t)g * 128 + t], s2);
        }
        if (t == 0) atomicAdd(&gecnt[g], (float)EPB);
    } else {
        int j = 0;
        while (j < EPB) {
            const int g = gidx[j];
            int j2 = j;
            float s = 0.f;
            while (j2 < EPB && gidx[j2] == g) { s += e1L[j2 * 256 + t]; j2++; }
            atomicAdd(&ge1[(size_t)g * 256 + t], s);
            if (t < 128) {
                float s2 = 0.f;
                for (int jj = j; jj < j2; jj++) s2 += e2L[jj * 128 + t];
                atomicAdd(&ge2[(size_t)g * 128 + t], s2);
            }
            if (t == 0) atomicAdd(&gecnt[g], (float)(j2 - j));
            j = j2;
        }
    }
}

// ---------------------------------------------------------------------------
// Node kernel: per (node,half) wave task -- gather incident edges, recompute
// e1 rows fp32 (We1 staged in LDS, e-row broadcast via __shfl), gather e2
// rows bf16; then n1/n2 MLPs and per-graph fp32 atomic sums.
// ---------------------------------------------------------------------------
#define NPB 8  // nodes per block; 50000 % 8 == 0

__global__ __launch_bounds__(256) void node_kernel(
    const float* __restrict__ x,            // [N,64]
    const int* __restrict__ node_graph,     // sorted
    const int* __restrict__ r_start, const int* __restrict__ s_start,
    const int* __restrict__ r_edges, const int* __restrict__ s_edges,
    const float* __restrict__ e,            // [E,32]
    const __hip_bfloat162* __restrict__ e2bf,  // [E,64]
    const float* __restrict__ We1, const float* __restrict__ be1,
    const float* __restrict__ Wn1, const float* __restrict__ Win1,
    const float* __restrict__ Wout1, const float* __restrict__ bn1,
    const float* __restrict__ Wn2, const float* __restrict__ Win2,
    const float* __restrict__ Wout2, const float* __restrict__ bn2,
    float* __restrict__ gn1, float* __restrict__ gn2, float* __restrict__ gncnt)
{
    __shared__ float Wst[32 * 256];    // 32 KB: We1 staging; ALIASED by n1L/n2L after gather
    __shared__ float xL[NPB * 64];     // 2 KB
    __shared__ float i1L[NPB * 256];   // 8 KB
    __shared__ float o1L[NPB * 256];   // 8 KB
    __shared__ float i2L[NPB * 128];   // 4 KB
    __shared__ float o2L[NPB * 128];   // 4 KB
    __shared__ int gI[NPB];
    __shared__ int stR[NPB + 1], stS[NPB + 1];

    const int t = threadIdx.x;
    const long n0 = (long)blockIdx.x * NPB;

    // stage We1 (8192 floats) via float4
    for (int i = t; i < 2048; i += 256)
        *(float4*)&Wst[i * 4] = *(const float4*)&We1[(size_t)i * 4];
    for (int i = t; i < NPB * 16; i += 256)
        *(float4*)&xL[i * 4] = *(const float4*)&x[n0 * 64 + i * 4];
    if (t < NPB) gI[t] = node_graph[n0 + t];
    if (t <= NPB) { stR[t] = r_start[n0 + t]; stS[t] = s_start[n0 + t]; }
    __syncthreads();

    // ---- gather: wave w handles nodes {2w, 2w+1} x {recv, send}
    {
        const int wave = t >> 6, lane = t & 63;
        const float4 bb = *(const float4*)&be1[lane * 4];  // e1 channels 4*lane..+3
        #pragma unroll
        for (int task = 0; task < 4; task++) {
            const int j = wave * 2 + (task & 1);
            const int half = task >> 1;
            const int b0 = __builtin_amdgcn_readfirstlane(half ? stS[j] : stR[j]);
            const int b1 = __builtin_amdgcn_readfirstlane(half ? stS[j + 1] : stR[j + 1]);
            const int* el = half ? s_edges : r_edges;
            float4 s1 = {0.f, 0.f, 0.f, 0.f};
            float s2x = 0.f, s2y = 0.f;
            int ii = b0;
            for (; ii + 1 < b1; ii += 2) {
                const int eA = el[ii], eB = el[ii + 1];
                // lanes 0-31 hold row A, lanes 32-63 hold row B
                const int eid = (lane < 32) ? eA : eB;
                const float ev = e[(size_t)eid * 32 + (lane & 31)];
                const float2 wA = __bfloat1622float2(e2bf[(size_t)eA * 64 + lane]);
                const float2 wB = __bfloat1622float2(e2bf[(size_t)eB * 64 + lane]);
                s2x += wA.x + wB.x; s2y += wA.y + wB.y;
                float4 zA = bb, zB = bb;
                #pragma unroll
                for (int k = 0; k < 32; k++) {
                    const float ekA = __shfl(ev, k, 64);
                    const float ekB = __shfl(ev, 32 + k, 64);
                    const float4 w4 = *(const float4*)&Wst[k * 256 + 4 * lane];
                    zA.x = fmaf(ekA, w4.x, zA.x); zB.x = fmaf(ekB, w4.x, zB.x);
                    zA.y = fmaf(ekA, w4.y, zA.y); zB.y = fmaf(ekB, w4.y, zB.y);
                    zA.z = fmaf(ekA, w4.z, zA.z); zB.z = fmaf(ekB, w4.z, zB.z);
                    zA.w = fmaf(ekA, w4.w, zA.w); zB.w = fmaf(ekB, w4.w, zB.w);
                }
                s1.x += fmaxf(zA.x, 0.f) + fmaxf(zB.x, 0.f);
                s1.y += fmaxf(zA.y, 0.f) + fmaxf(zB.y, 0.f);
                s1.z += fmaxf(zA.z, 0.f) + fmaxf(zB.z, 0.f);
                s1.w += fmaxf(zA.w, 0.f) + fmaxf(zB.w, 0.f);
            }
            if (ii < b1) {
                const int eA = el[ii];
                const float ev = (lane < 32) ? e[(size_t)eA * 32 + (lane & 31)] : 0.f;
                const float2 wA = __bfloat1622float2(e2bf[(size_t)eA * 64 + lane]);
                s2x += wA.x; s2y += wA.y;
                float4 zA = bb;
                #pragma unroll
                for (int k = 0; k < 32; k++) {
                    const float ekA = __shfl(ev, k, 64);
                    const float4 w4 = *(const float4*)&Wst[k * 256 + 4 * lane];
                    zA.x = fmaf(ekA, w4.x, zA.x);
                    zA.y = fmaf(ekA, w4.y, zA.y);
                    zA.z = fmaf(ekA, w4.z, zA.z);
                    zA.w = fmaf(ekA, w4.w, zA.w);
                }
                s1.x += fmaxf(zA.x, 0.f);
                s1.y += fmaxf(zA.y, 0.f);
                s1.z += fmaxf(zA.z, 0.f);
                s1.w += fmaxf(zA.w, 0.f);
            }
            const float inv = 1.f / fmaxf((float)(b1 - b0), 1.f);
            float* d1 = half ? o1L : i1L;
            float* d2 = half ? o2L : i2L;
            float4 m1; m1.x = s1.x * inv; m1.y = s1.y * inv; m1.z = s1.z * inv; m1.w = s1.w * inv;
            *(float4*)&d1[j * 256 + 4 * lane] = m1;
            *(float2*)&d2[j * 128 + 2 * lane] = make_float2(s2x * inv, s2y * inv);
        }
    }
    __syncthreads();

    // Wst no longer needed -> alias n1L/n2L into it
    float* n1L = Wst;               // NPB*256 = 2048 floats
    float* n2L = Wst + NPB * 256;   // NPB*128 = 1024 floats

    // ---- n1: thread = 4 channels, 2 nodes
    {
        const int c0 = (t & 63) * 4;
        const int jb = (t >> 6) * 2;
        float4 acc[2];
        const float4 b4 = *(const float4*)&bn1[c0];
        #pragma unroll
        for (int j = 0; j < 2; j++) acc[j] = b4;
        for (int k = 0; k < 64; k += 4) {
            float4 v[2];
            #pragma unroll
            for (int j = 0; j < 2; j++) v[j] = *(const float4*)&xL[(jb + j) * 64 + k];
            #pragma unroll
            for (int kk = 0; kk < 4; kk++) {
                const float4 w = *(const float4*)&Wn1[(size_t)(k + kk) * 256 + c0];
                #pragma unroll
                for (int j = 0; j < 2; j++) {
                    const float vv = ((const float*)&v[j])[kk];
                    acc[j].x = fmaf(vv, w.x, acc[j].x);
                    acc[j].y = fmaf(vv, w.y, acc[j].y);
                    acc[j].z = fmaf(vv, w.z, acc[j].z);
                    acc[j].w = fmaf(vv, w.w, acc[j].w);
                }
            }
        }
        for (int k = 0; k < 256; k += 4) {
            float4 v[2];
            #pragma unroll
            for (int j = 0; j < 2; j++) v[j] = *(const float4*)&i1L[(jb + j) * 256 + k];
            #pragma unroll
            for (int kk = 0; kk < 4; kk++) {
                const float4 w = *(const float4*)&Win1[(size_t)(k + kk) * 256 + c0];
                #pragma unroll
                for (int j = 0; j < 2; j++) {
                    const float vv = ((const float*)&v[j])[kk];
                    acc[j].x = fmaf(vv, w.x, acc[j].x);
                    acc[j].y = fmaf(vv, w.y, acc[j].y);
                    acc[j].z = fmaf(vv, w.z, acc[j].z);
                    acc[j].w = fmaf(vv, w.w, acc[j].w);
                }
            }
        }
        for (int k = 0; k < 256; k += 4) {
            float4 v[2];
            #pragma unroll
            for (int j = 0; j < 2; j++) v[j] = *(const float4*)&o1L[(jb + j) * 256 + k];
            #pragma unroll
            for (int kk = 0; kk < 4; kk++) {
                const float4 w = *(const float4*)&Wout1[(size_t)(k + kk) * 256 + c0];
                #pragma unroll
                for (int j = 0; j < 2; j++) {
                    const float vv = ((const float*)&v[j])[kk];
                    acc[j].x = fmaf(vv, w.x, acc[j].x);
                    acc[j].y = fmaf(vv, w.y, acc[j].y);
                    acc[j].z = fmaf(vv, w.z, acc[j].z);
                    acc[j].w = fmaf(vv, w.w, acc[j].w);
                }
            }
        }
        #pragma unroll
        for (int j = 0; j < 2; j++) {
            float4 r;
            r.x = fmaxf(acc[j].x, 0.f); r.y = fmaxf(acc[j].y, 0.f);
            r.z = fmaxf(acc[j].z, 0.f); r.w = fmaxf(acc[j].w, 0.f);
            *(float4*)&n1L[(jb + j) * 256 + c0] = r;
        }
    }
    __syncthreads();

    // ---- per-graph n1 sums (fp32, sorted-run aggregation)
    if (gI[0] == gI[NPB - 1]) {
        float s = 0.f;
        #pragma unroll
        for (int j = 0; j < NPB; j++) s += n1L[j * 256 + t];
        atomicAdd(&gn1[(size_t)gI[0] * 256 + t], s);
        if (t == 0) atomicAdd(&gncnt[gI[0]], (float)NPB);
    } else {
        int j = 0;
        while (j < NPB) {
            const int g = gI[j];
            int j2 = j;
            float s = 0.f;
            while (j2 < NPB && gI[j2] == g) { s += n1L[j2 * 256 + t]; j2++; }
            atomicAdd(&gn1[(size_t)g * 256 + t], s);
            if (t == 0) atomicAdd(&gncnt[g], (float)(j2 - j));
            j = j2;
        }
    }

    // ---- n2: thread = 4 channels, 1 node
    {
        const int c0 = (t & 31) * 4;
        const int jb = t >> 5;
        float4 acc;
        acc = *(const float4*)&bn2[c0];
        for (int k = 0; k < 256; k += 4) {
            const float4 v = *(const float4*)&n1L[jb * 256 + k];
            #pragma unroll
            for (int kk = 0; kk < 4; kk++) {
                const float4 w = *(const float4*)&Wn2[(size_t)(k + kk) * 128 + c0];
                const float vv = ((const float*)&v)[kk];
                acc.x = fmaf(vv, w.x, acc.x);
                acc.y = fmaf(vv, w.y, acc.y);
                acc.z = fmaf(vv, w.z, acc.z);
                acc.w = fmaf(vv, w.w, acc.w);
            }
        }
        for (int k = 0; k < 128; k += 4) {
            const float4 v = *(const float4*)&i2L[jb * 128 + k];
            #pragma unroll
            for (int kk = 0; kk < 4; kk++) {
                const float4 w = *(const float4*)&Win2[(size_t)(k + kk) * 128 + c0];
                const float vv = ((const float*)&v)[kk];
                acc.x = fmaf(vv, w.x, acc.x);
                acc.y = fmaf(vv, w.y, acc.y);
                acc.z = fmaf(vv, w.z, acc.z);
                acc.w = fmaf(vv, w.w, acc.w);
            }
        }
        for (int k = 0; k < 128; k += 4) {
            const float4 v = *(const float4*)&o2L[jb * 128 + k];
            #pragma unroll
            for (int kk = 0; kk < 4; kk++) {
                const float4 w = *(const float4*)&Wout2[(size_t)(k + kk) * 128 + c0];
                const float vv = ((const float*)&v)[kk];
                acc.x = fmaf(vv, w.x, acc.x);
                acc.y = fmaf(vv, w.y, acc.y);
                acc.z = fmaf(vv, w.z, acc.z);
                acc.w = fmaf(vv, w.w, acc.w);
            }
        }
        float4 r;
        r.x = fmaxf(acc.x, 0.f); r.y = fmaxf(acc.y, 0.f);
        r.z = fmaxf(acc.z, 0.f); r.w = fmaxf(acc.w, 0.f);
        *(float4*)&n2L[jb * 128 + c0] = r;
    }
    __syncthreads();

    // ---- per-graph n2 sums (fp32)
    if (t < 128) {
        if (gI[0] == gI[NPB - 1]) {
            float s = 0.f;
            #pragma unroll
            for (int j = 0; j < NPB; j++) s += n2L[j * 128 + t];
            atomicAdd(&gn2[(size_t)gI[0] * 128 + t], s);
        } else {
            int j = 0;
            while (j < NPB) {
                const int g = gI[j];
                int j2 = j;
                float s = 0.f;
                while (j2 < NPB && gI[j2] == g) { s += n2L[j2 * 128 + t]; j2++; }
                atomicAdd(&gn2[(size_t)g * 128 + t], s);
                j = j2;
            }
        }
    }
}

// ---------------------------------------------------------------------------
// Graph kernel: one block per graph. u1, u2, state_value, action MLP, output.
// ---------------------------------------------------------------------------
__global__ __launch_bounds__(256) void graph_kernel(
    const float* __restrict__ u,   // [B,64]
    const float* __restrict__ a,   // [B,8]
    const float* __restrict__ ge1, const float* __restrict__ ge2,
    const float* __restrict__ gecnt,
    const float* __restrict__ gn1, const float* __restrict__ gn2,
    const float* __restrict__ gncnt,
    const float* __restrict__ Wg1, const float* __restrict__ Wgn1,
    const float* __restrict__ Wge1, const float* __restrict__ bg1,
    const float* __restrict__ Wg2, const float* __restrict__ Wgn2,
    const float* __restrict__ Wge2, const float* __restrict__ bg2,
    const float* __restrict__ Wga, const float* __restrict__ bga,
    const float* __restrict__ Wa1, const float* __restrict__ ba1,
    const float* __restrict__ Wa2, const float* __restrict__ ba2,
    const float* __restrict__ Wa3, const float* __restrict__ ba3,
    float* __restrict__ out)
{
    const int g = blockIdx.x;
    const int t = threadIdx.x;
    __shared__ float uL[64], mn1[256], me1[256], mn2[128], me2[128];
    __shared__ float u1L[256], u2L[128], hL[144], h1L[256], h2L[256];
    __shared__ float red[4];

    const float ec = 1.f / fmaxf(gecnt[g], 1.f);
    const float nc = 1.f / fmaxf(gncnt[g], 1.f);
    if (t < 64) uL[t] = u[(size_t)g * 64 + t];
    mn1[t] = gn1[(size_t)g * 256 + t] * nc;
    me1[t] = ge1[(size_t)g * 256 + t] * ec;
    if (t < 128) {
        mn2[t] = gn2[(size_t)g * 128 + t] * nc;
        me2[t] = ge2[(size_t)g * 128 + t] * ec;
    }
    if (t >= 136 && t < 144) hL[t] = 0.f;
    __syncthreads();

    // u1 = relu(u@Wg1 + mn1@Wgn1 + me1@Wge1 + bg1)
    {
        float acc = bg1[t];
        for (int k = 0; k < 64; k++)  acc = fmaf(uL[k],  Wg1[(size_t)k * 256 + t], acc);
        for (int k = 0; k < 256; k++) acc = fmaf(mn1[k], Wgn1[(size_t)k * 256 + t], acc);
        for (int k = 0; k < 256; k++) acc = fmaf(me1[k], Wge1[(size_t)k * 256 + t], acc);
        u1L[t] = fmaxf(acc, 0.f);
    }
    __syncthreads();
    // u2 = relu(u1@Wg2 + mn2@Wgn2 + me2@Wge2 + bg2)
    if (t < 128) {
        float acc = bg2[t];
        for (int k = 0; k < 256; k++) acc = fmaf(u1L[k], Wg2[(size_t)k * 128 + t], acc);
        for (int k = 0; k < 128; k++) acc = fmaf(mn2[k], Wgn2[(size_t)k * 128 + t], acc);
        for (int k = 0; k < 128; k++) acc = fmaf(me2[k], Wge2[(size_t)k * 128 + t], acc);
        u2L[t] = fmaxf(acc, 0.f);
    }
    __syncthreads();
    // state_value + concat(a)
    if (t < 128) {
        float acc = bga[t];
        for (int k = 0; k < 128; k++) acc = fmaf(u2L[k], Wga[(size_t)k * 128 + t], acc);
        hL[t] = acc;
    }
    if (t >= 128 && t < 136) hL[t] = a[(size_t)g * 8 + (t - 128)];
    __syncthreads();
    // h1 = relu(h@Wa1+ba1)
    {
        float acc = ba1[t];
        for (int k = 0; k < 136; k++) acc = fmaf(hL[k], Wa1[(size_t)k * 256 + t], acc);
        h1L[t] = fmaxf(acc, 0.f);
    }
    __syncthreads();
    // h2 = relu(h1@Wa2+ba2)
    {
        float acc = ba2[t];
        for (int k = 0; k < 256; k++) acc = fmaf(h1L[k], Wa2[(size_t)k * 256 + t], acc);
        h2L[t] = fmaxf(acc, 0.f);
    }
    __syncthreads();
    // out = h2 @ Wa3 + ba3
    {
        float p = h2L[t] * Wa3[t];
        for (int off = 32; off > 0; off >>= 1) p += __shfl_down(p, off, 64);
        if ((t & 63) == 0) red[t >> 6] = p;
        __syncthreads();
        if (t == 0) out[g] = red[0] + red[1] + red[2] + red[3] + ba3[0];
    }
}

// ---------------------------------------------------------------------------
extern "C" void kernel_launch(void* const* d_in, const int* in_sizes, int n_in,
                              void* d_out, int out_size, void* d_ws, size_t ws_size,
                              hipStream_t stream) {
    const float* x          = (const float*)d_in[0];
    const float* e          = (const float*)d_in[1];
    const float* u          = (const float*)d_in[2];
    const float* a          = (const float*)d_in[3];
    const int*   senders    = (const int*)d_in[4];
    const int*   receivers  = (const int*)d_in[5];
    const int*   node_graph = (const int*)d_in[6];
    const int*   edge_graph = (const int*)d_in[7];
    const float* We1 = (const float*)d_in[8];  const float* be1 = (const float*)d_in[9];
    const float* Wn1 = (const float*)d_in[10]; const float* Win1 = (const float*)d_in[11];
    const float* Wout1 = (const float*)d_in[12]; const float* bn1 = (const float*)d_in[13];
    const float* Wg1 = (const float*)d_in[14]; const float* Wgn1 = (const float*)d_in[15];
    const float* Wge1 = (const float*)d_in[16]; const float* bg1 = (const float*)d_in[17];
    const float* We2 = (const float*)d_in[18]; const float* be2 = (const float*)d_in[19];
    const float* Wn2 = (const float*)d_in[20]; const float* Win2 = (const float*)d_in[21];
    const float* Wout2 = (const float*)d_in[22]; const float* bn2 = (const float*)d_in[23];
    const float* Wg2 = (const float*)d_in[24]; const float* Wgn2 = (const float*)d_in[25];
    const float* Wge2 = (const float*)d_in[26]; const float* bg2 = (const float*)d_in[27];
    const float* Wga = (const float*)d_in[28]; const float* bga = (const float*)d_in[29];
    const float* Wa1 = (const float*)d_in[30]; const float* ba1 = (const float*)d_in[31];
    const float* Wa2 = (const float*)d_in[32]; const float* ba2 = (const float*)d_in[33];
    const float* Wa3 = (const float*)d_in[34]; const float* ba3 = (const float*)d_in[35];

    // ---- workspace layout (~136 MB total; R4's 155 MB fit) -----------------
    char* p = (char*)d_ws;
    int* r_cnt = (int*)p;      p += N_NODES * 4;
    int* s_cnt = (int*)p;      p += N_NODES * 4;
    float* ge1 = (float*)p;    p += (size_t)N_GRAPHS * 256 * 4;
    float* ge2 = (float*)p;    p += (size_t)N_GRAPHS * 128 * 4;
    float* gecnt = (float*)p;  p += N_GRAPHS * 4;
    float* gn1 = (float*)p;    p += (size_t)N_GRAPHS * 256 * 4;
    float* gn2 = (float*)p;    p += (size_t)N_GRAPHS * 128 * 4;
    float* gncnt = (float*)p;  p += N_GRAPHS * 4;
    const size_t zero_bytes = p - (char*)d_ws;
    int* r_ps = (int*)p;       p += N_NODES * 4;
    int* s_ps = (int*)p;       p += N_NODES * 4;
    int* r_bt = (int*)p;       p += 128 * 4;
    int* s_bt = (int*)p;       p += 128 * 4;
    int* r_start = (int*)p;    p += (N_NODES + 4) * 4;
    int* s_start = (int*)p;    p += (N_NODES + 4) * 4;
    int* r_cur = (int*)p;      p += N_NODES * 4;
    int* s_cur = (int*)p;      p += N_NODES * 4;
    int* r_edges = (int*)p;    p += (size_t)N_EDGES * 4;
    int* s_edges = (int*)p;    p += (size_t)N_EDGES * 4;
    __hip_bfloat162* e2bf = (__hip_bfloat162*)p; p += (size_t)N_EDGES * 64 * 4;  // 128 MB

    hipMemsetAsync(d_ws, 0, zero_bytes, stream);

    // ---- CSR build ---------------------------------------------------------
    const int EB = (N_EDGES + 255) / 256;
    count_kernel<<<EB, 256, 0, stream>>>(receivers, senders, r_cnt, s_cnt);
    scan1_kernel<<<dim3(SCAN_NB, 2), SCAN_B, 0, stream>>>(r_cnt, s_cnt, r_ps, s_ps, r_bt, s_bt);
    scan2_kernel<<<1, 64, 0, stream>>>(r_bt, s_bt);
    scan3_kernel<<<(N_NODES + 255) / 256, 256, 0, stream>>>(
        r_ps, s_ps, r_bt, s_bt, r_start, s_start, r_cur, s_cur);
    fill_kernel<<<EB, 256, 0, stream>>>(receivers, senders, r_cur, s_cur, r_edges, s_edges);

    // ---- main pipeline -----------------------------------------------------
    edge_kernel<<<N_EDGES / EPB, 256, 0, stream>>>(
        e, edge_graph, We1, be1, We2, be2, e2bf, ge1, ge2, gecnt);

    node_kernel<<<N_NODES / NPB, 256, 0, stream>>>(
        x, node_graph, r_start, s_start, r_edges, s_edges, e, e2bf,
        We1, be1, Wn1, Win1, Wout1, bn1, Wn2, Win2, Wout2, bn2, gn1, gn2, gncnt);

    graph_kernel<<<N_GRAPHS, 256, 0, stream>>>(
        u, a, ge1, ge2, gecnt, gn1, gn2, gncnt,
        Wg1, Wgn1, Wge1, bg1, Wg2, Wgn2, Wge2, bg2,
        Wga, bga, Wa1, ba1, Wa2, ba2, Wa3, ba3, (float*)d_out);
}

// Round 7
// 1451.792 us; speedup vs baseline: 1.7090x; 1.7090x over previous
//
#include <hip/hip_runtime.h>
#include <hip/hip_bf16.h>

// Problem constants (fixed by reference)
#define N_NODES 50000
#define N_EDGES 500000
#define N_GRAPHS 512

// ---------------------------------------------------------------------------
// Packed fixed-point atomics: FOUR non-negative fp32 channels packed as u16
// fixed point (scale 2^11) into one u64 atomicAdd. Valid: post-ReLU >= 0,
// per-node channel sums bounded ~12 -> max lane 24.6K << 65536 (no carry).
// Quantization 2^-11 -> ~1e-4 at output vs 3.4e-3 threshold. (R4: absmax 0.0)
// ---------------------------------------------------------------------------
#define FXS16 2048.0f
#define FXI16 4.8828125e-4f  // 2^-11

__device__ __forceinline__ unsigned long long pk16x4(float4 v) {
    const unsigned long long a = (unsigned int)fmaf(v.x, FXS16, 0.5f);
    const unsigned long long b = (unsigned int)fmaf(v.y, FXS16, 0.5f);
    const unsigned long long c = (unsigned int)fmaf(v.z, FXS16, 0.5f);
    const unsigned long long d = (unsigned int)fmaf(v.w, FXS16, 0.5f);
    return a | (b << 16) | (c << 32) | (d << 48);
}

// ---------------------------------------------------------------------------
// Edge kernel (EPB=32): per edge e1=relu(e@We1+be1)[256], e2=relu(e1@We2)
// [128]; u16x4-packed u64 atomic scatter to node accumulators; per-graph
// fp32 atomic sums. EPB=32 halves per-edge weight streaming from L2
// (identified R6 bottleneck: 160KB weights per block). LDS 52.4 KB -> 3
// blocks/CU (12 waves).
// ---------------------------------------------------------------------------
#define EPB 32  // edges per block; 500000 % 32 == 0 -> 15625 blocks

__global__ __launch_bounds__(256) void edge_kernel(
    const float* __restrict__ e,          // [E,32]
    const int* __restrict__ senders,
    const int* __restrict__ receivers,
    const int* __restrict__ edge_graph,   // sorted
    const float* __restrict__ We1, const float* __restrict__ be1,   // [32,256],[256]
    const float* __restrict__ We2, const float* __restrict__ be2,   // [256,128],[128]
    unsigned long long* __restrict__ inc1u, unsigned long long* __restrict__ out1u, // [N,64]
    unsigned long long* __restrict__ inc2u, unsigned long long* __restrict__ out2u, // [N,32]
    float* __restrict__ rcnt, float* __restrict__ scnt,             // [N]
    float* __restrict__ ge1, float* __restrict__ ge2, float* __restrict__ gecnt)
{
    __shared__ float eL[EPB * 32];     // 4 KB
    __shared__ float e1L[EPB * 256];   // 32 KB
    __shared__ float e2L[EPB * 128];   // 16 KB
    __shared__ int ridx[EPB], sidx[EPB], gidx[EPB];

    const int t = threadIdx.x;
    const long e0 = (long)blockIdx.x * EPB;

    for (int i = t; i < EPB * 32; i += 256) eL[i] = e[e0 * 32 + i];
    if (t < EPB) {
        ridx[t] = receivers[e0 + t];
        sidx[t] = senders[e0 + t];
        gidx[t] = edge_graph[e0 + t];
    }
    __syncthreads();

    // ---- e1 = relu(e @ We1 + be1). thread: 4 channels, 8 edges.
    {
        const int c0 = (t & 63) * 4;
        const int jb = (t >> 6) * 8;
        float4 acc[8];
        const float4 b4 = *(const float4*)&be1[c0];
        #pragma unroll
        for (int j = 0; j < 8; j++) acc[j] = b4;
        for (int k = 0; k < 32; k += 4) {
            float4 v[8];
            #pragma unroll
            for (int j = 0; j < 8; j++) v[j] = *(const float4*)&eL[(jb + j) * 32 + k];
            #pragma unroll
            for (int kk = 0; kk < 4; kk++) {
                const float4 w = *(const float4*)&We1[(size_t)(k + kk) * 256 + c0];
                #pragma unroll
                for (int j = 0; j < 8; j++) {
                    const float vv = ((const float*)&v[j])[kk];
                    acc[j].x = fmaf(vv, w.x, acc[j].x);
                    acc[j].y = fmaf(vv, w.y, acc[j].y);
                    acc[j].z = fmaf(vv, w.z, acc[j].z);
                    acc[j].w = fmaf(vv, w.w, acc[j].w);
                }
            }
        }
        #pragma unroll
        for (int j = 0; j < 8; j++) {
            float4 r;
            r.x = fmaxf(acc[j].x, 0.f); r.y = fmaxf(acc[j].y, 0.f);
            r.z = fmaxf(acc[j].z, 0.f); r.w = fmaxf(acc[j].w, 0.f);
            *(float4*)&e1L[(jb + j) * 256 + c0] = r;
        }
    }
    __syncthreads();

    // ---- e2 = relu(e1 @ We2 + be2). thread: 4 channels, 4 edges.
    {
        const int c0 = (t & 31) * 4;
        const int jb = (t >> 5) * 4;
        float4 acc[4];
        const float4 b4 = *(const float4*)&be2[c0];
        #pragma unroll
        for (int j = 0; j < 4; j++) acc[j] = b4;
        for (int k = 0; k < 256; k += 4) {
            float4 v[4];
            #pragma unroll
            for (int j = 0; j < 4; j++) v[j] = *(const float4*)&e1L[(jb + j) * 256 + k];
            #pragma unroll
            for (int kk = 0; kk < 4; kk++) {
                const float4 w = *(const float4*)&We2[(size_t)(k + kk) * 128 + c0];
                #pragma unroll
                for (int j = 0; j < 4; j++) {
                    const float vv = ((const float*)&v[j])[kk];
                    acc[j].x = fmaf(vv, w.x, acc[j].x);
                    acc[j].y = fmaf(vv, w.y, acc[j].y);
                    acc[j].z = fmaf(vv, w.z, acc[j].z);
                    acc[j].w = fmaf(vv, w.w, acc[j].w);
                }
            }
        }
        #pragma unroll
        for (int j = 0; j < 4; j++) {
            float4 r;
            r.x = fmaxf(acc[j].x, 0.f); r.y = fmaxf(acc[j].y, 0.f);
            r.z = fmaxf(acc[j].z, 0.f); r.w = fmaxf(acc[j].w, 0.f);
            *(float4*)&e2L[(jb + j) * 128 + c0] = r;
        }
    }
    __syncthreads();

    // ---- scatter e1 (u64 = 4 channels): 2 dests x 64 words x 2 edge-parities
    {
        const int w = t & 63;            // u64 word = channels 4w..4w+3
        const int ep = (t >> 6) & 1;     // edge parity
        unsigned long long* arr = (t < 128) ? inc1u : out1u;
        const int* idx = (t < 128) ? ridx : sidx;
        #pragma unroll
        for (int jj = 0; jj < EPB / 2; jj++) {
            const int j = jj * 2 + ep;
            const float4 v = *(const float4*)&e1L[j * 256 + 4 * w];
            atomicAdd(&arr[(size_t)idx[j] * 64 + w], pk16x4(v));
        }
    }
    // ---- scatter e2: 2 dests x 32 words x 4 edge-groups
    {
        const int w = t & 31;
        const int eq = (t >> 5) & 3;
        unsigned long long* arr = (t < 128) ? inc2u : out2u;
        const int* idx = (t < 128) ? ridx : sidx;
        #pragma unroll
        for (int jj = 0; jj < EPB / 4; jj++) {
            const int j = jj * 4 + eq;
            const float4 v = *(const float4*)&e2L[j * 128 + 4 * w];
            atomicAdd(&arr[(size_t)idx[j] * 32 + w], pk16x4(v));
        }
    }
    // ---- per-graph sums (edge_graph sorted: usually one run per block), fp32
    if (gidx[0] == gidx[EPB - 1]) {
        const int g = gidx[0];
        float s = 0.f;
        #pragma unroll
        for (int j = 0; j < EPB; j++) s += e1L[j * 256 + t];
        atomicAdd(&ge1[(size_t)g * 256 + t], s);
        if (t < 128) {
            float s2 = 0.f;
            #pragma unroll
            for (int j = 0; j < EPB; j++) s2 += e2L[j * 128 + t];
            atomicAdd(&ge2[(size_t)g * 128 + t], s2);
        }
        if (t == 0) atomicAdd(&gecnt[g], (float)EPB);
    } else {
        int j = 0;
        while (j < EPB) {
            const int g = gidx[j];
            int j2 = j;
            float s = 0.f;
            while (j2 < EPB && gidx[j2] == g) { s += e1L[j2 * 256 + t]; j2++; }
            atomicAdd(&ge1[(size_t)g * 256 + t], s);
            if (t < 128) {
                float s2 = 0.f;
                for (int jj = j; jj < j2; jj++) s2 += e2L[jj * 128 + t];
                atomicAdd(&ge2[(size_t)g * 128 + t], s2);
            }
            if (t == 0) atomicAdd(&gecnt[g], (float)(j2 - j));
            j = j2;
        }
    }
    if (t < EPB) {
        atomicAdd(&rcnt[ridx[t]], 1.f);
        atomicAdd(&scnt[sidx[t]], 1.f);
    }
}

// ---------------------------------------------------------------------------
// Node kernel (R4-proven): n1 = relu(x@Wn1 + inc1@Win1 + out1@Wout1 + bn1),
//              n2 = relu(n1@Wn2 + inc2@Win2 + out2@Wout2 + bn2),
// per-graph sums of n1,n2 (node_graph sorted, fp32 atomics).
// ---------------------------------------------------------------------------
#define NPB 16  // nodes per block; 50000 % 16 == 0

__global__ __launch_bounds__(256) void node_kernel(
    const float* __restrict__ x,            // [N,64]
    const int* __restrict__ node_graph,     // sorted
    const unsigned long long* __restrict__ inc1u, const unsigned long long* __restrict__ out1u,
    const unsigned long long* __restrict__ inc2u, const unsigned long long* __restrict__ out2u,
    const float* __restrict__ rcnt, const float* __restrict__ scnt,
    const float* __restrict__ Wn1, const float* __restrict__ Win1,
    const float* __restrict__ Wout1, const float* __restrict__ bn1,
    const float* __restrict__ Wn2, const float* __restrict__ Win2,
    const float* __restrict__ Wout2, const float* __restrict__ bn2,
    float* __restrict__ gn1, float* __restrict__ gn2, float* __restrict__ gncnt)
{
    __shared__ float xL[NPB * 64];     // 4 KB
    __shared__ float i1L[NPB * 256];   // 16 KB
    __shared__ float o1L[NPB * 256];   // 16 KB
    __shared__ float i2L[NPB * 128];   // 8 KB
    __shared__ float o2L[NPB * 128];   // 8 KB
    __shared__ float n1L[NPB * 256];   // 16 KB
    __shared__ float n2L[NPB * 128];   // 8 KB
    __shared__ int gI[NPB];
    __shared__ float rrcp[NPB], srcp[NPB];

    const int t = threadIdx.x;
    const long n0 = (long)blockIdx.x * NPB;

    for (int i = t; i < NPB * 16; i += 256)
        *(float4*)&xL[i * 4] = *(const float4*)&x[n0 * 64 + i * 4];
    if (t < NPB) {
        gI[t] = node_graph[n0 + t];
        rrcp[t] = 1.f / fmaxf(rcnt[n0 + t], 1.f);
        srcp[t] = 1.f / fmaxf(scnt[n0 + t], 1.f);
    }
    __syncthreads();
    // decode u16x4 fixed-point accumulators -> scaled means in LDS
    for (int i = t; i < NPB * 64; i += 256) {          // 4 iters
        const int j = i >> 6, w = i & 63;
        const size_t n = (size_t)(n0 + j);
        const unsigned long long av = inc1u[n * 64 + w];
        const unsigned long long bv = out1u[n * 64 + w];
        const float rr = rrcp[j] * FXI16, sr = srcp[j] * FXI16;
        float4 af, bf;
        af.x = (float)(unsigned int)(av & 0xFFFF) * rr;
        af.y = (float)(unsigned int)((av >> 16) & 0xFFFF) * rr;
        af.z = (float)(unsigned int)((av >> 32) & 0xFFFF) * rr;
        af.w = (float)(unsigned int)(av >> 48) * rr;
        bf.x = (float)(unsigned int)(bv & 0xFFFF) * sr;
        bf.y = (float)(unsigned int)((bv >> 16) & 0xFFFF) * sr;
        bf.z = (float)(unsigned int)((bv >> 32) & 0xFFFF) * sr;
        bf.w = (float)(unsigned int)(bv >> 48) * sr;
        *(float4*)&i1L[j * 256 + 4 * w] = af;
        *(float4*)&o1L[j * 256 + 4 * w] = bf;
    }
    for (int i = t; i < NPB * 32; i += 256) {          // 2 iters
        const int j = i >> 5, w = i & 31;
        const size_t n = (size_t)(n0 + j);
        const unsigned long long av = inc2u[n * 32 + w];
        const unsigned long long bv = out2u[n * 32 + w];
        const float rr = rrcp[j] * FXI16, sr = srcp[j] * FXI16;
        float4 af, bf;
        af.x = (float)(unsigned int)(av & 0xFFFF) * rr;
        af.y = (float)(unsigned int)((av >> 16) & 0xFFFF) * rr;
        af.z = (float)(unsigned int)((av >> 32) & 0xFFFF) * rr;
        af.w = (float)(unsigned int)(av >> 48) * rr;
        bf.x = (float)(unsigned int)(bv & 0xFFFF) * sr;
        bf.y = (float)(unsigned int)((bv >> 16) & 0xFFFF) * sr;
        bf.z = (float)(unsigned int)((bv >> 32) & 0xFFFF) * sr;
        bf.w = (float)(unsigned int)(bv >> 48) * sr;
        *(float4*)&i2L[j * 128 + 4 * w] = af;
        *(float4*)&o2L[j * 128 + 4 * w] = bf;
    }
    __syncthreads();

    // ---- n1: thread = 4 channels, 4 nodes
    {
        const int c0 = (t & 63) * 4;
        const int jb = (t >> 6) * 4;
        float4 acc[4];
        const float4 b4 = *(const float4*)&bn1[c0];
        #pragma unroll
        for (int j = 0; j < 4; j++) acc[j] = b4;
        for (int k = 0; k < 64; k += 4) {
            float4 v[4];
            #pragma unroll
            for (int j = 0; j < 4; j++) v[j] = *(const float4*)&xL[(jb + j) * 64 + k];
            #pragma unroll
            for (int kk = 0; kk < 4; kk++) {
                const float4 w = *(const float4*)&Wn1[(size_t)(k + kk) * 256 + c0];
                #pragma unroll
                for (int j = 0; j < 4; j++) {
                    const float vv = ((const float*)&v[j])[kk];
                    acc[j].x = fmaf(vv, w.x, acc[j].x);
                    acc[j].y = fmaf(vv, w.y, acc[j].y);
                    acc[j].z = fmaf(vv, w.z, acc[j].z);
                    acc[j].w = fmaf(vv, w.w, acc[j].w);
                }
            }
        }
        for (int k = 0; k < 256; k += 4) {
            float4 v[4];
            #pragma unroll
            for (int j = 0; j < 4; j++) v[j] = *(const float4*)&i1L[(jb + j) * 256 + k];
            #pragma unroll
            for (int kk = 0; kk < 4; kk++) {
                const float4 w = *(const float4*)&Win1[(size_t)(k + kk) * 256 + c0];
                #pragma unroll
                for (int j = 0; j < 4; j++) {
                    const float vv = ((const float*)&v[j])[kk];
                    acc[j].x = fmaf(vv, w.x, acc[j].x);
                    acc[j].y = fmaf(vv, w.y, acc[j].y);
                    acc[j].z = fmaf(vv, w.z, acc[j].z);
                    acc[j].w = fmaf(vv, w.w, acc[j].w);
                }
            }
        }
        for (int k = 0; k < 256; k += 4) {
            float4 v[4];
            #pragma unroll
            for (int j = 0; j < 4; j++) v[j] = *(const float4*)&o1L[(jb + j) * 256 + k];
            #pragma unroll
            for (int kk = 0; kk < 4; kk++) {
                const float4 w = *(const float4*)&Wout1[(size_t)(k + kk) * 256 + c0];
                #pragma unroll
                for (int j = 0; j < 4; j++) {
                    const float vv = ((const float*)&v[j])[kk];
                    acc[j].x = fmaf(vv, w.x, acc[j].x);
                    acc[j].y = fmaf(vv, w.y, acc[j].y);
                    acc[j].z = fmaf(vv, w.z, acc[j].z);
                    acc[j].w = fmaf(vv, w.w, acc[j].w);
                }
            }
        }
        #pragma unroll
        for (int j = 0; j < 4; j++) {
            float4 r;
            r.x = fmaxf(acc[j].x, 0.f); r.y = fmaxf(acc[j].y, 0.f);
            r.z = fmaxf(acc[j].z, 0.f); r.w = fmaxf(acc[j].w, 0.f);
            *(float4*)&n1L[(jb + j) * 256 + c0] = r;
        }
    }
    __syncthreads();

    // ---- per-graph n1 sums (fp32, sorted-run aggregation)
    if (gI[0] == gI[NPB - 1]) {
        float s = 0.f;
        #pragma unroll
        for (int j = 0; j < NPB; j++) s += n1L[j * 256 + t];
        atomicAdd(&gn1[(size_t)gI[0] * 256 + t], s);
        if (t == 0) atomicAdd(&gncnt[gI[0]], (float)NPB);
    } else {
        int j = 0;
        while (j < NPB) {
            const int g = gI[j];
            int j2 = j;
            float s = 0.f;
            while (j2 < NPB && gI[j2] == g) { s += n1L[j2 * 256 + t]; j2++; }
            atomicAdd(&gn1[(size_t)g * 256 + t], s);
            if (t == 0) atomicAdd(&gncnt[g], (float)(j2 - j));
            j = j2;
        }
    }

    // ---- n2: thread = 4 channels, 2 nodes
    {
        const int c0 = (t & 31) * 4;
        const int jb = (t >> 5) * 2;
        float4 acc[2];
        const float4 b4 = *(const float4*)&bn2[c0];
        #pragma unroll
        for (int j = 0; j < 2; j++) acc[j] = b4;
        for (int k = 0; k < 256; k += 4) {
            float4 v[2];
            #pragma unroll
            for (int j = 0; j < 2; j++) v[j] = *(const float4*)&n1L[(jb + j) * 256 + k];
            #pragma unroll
            for (int kk = 0; kk < 4; kk++) {
                const float4 w = *(const float4*)&Wn2[(size_t)(k + kk) * 128 + c0];
                #pragma unroll
                for (int j = 0; j < 2; j++) {
                    const float vv = ((const float*)&v[j])[kk];
                    acc[j].x = fmaf(vv, w.x, acc[j].x);
                    acc[j].y = fmaf(vv, w.y, acc[j].y);
                    acc[j].z = fmaf(vv, w.z, acc[j].z);
                    acc[j].w = fmaf(vv, w.w, acc[j].w);
                }
            }
        }
        for (int k = 0; k < 128; k += 4) {
            float4 v[2];
            #pragma unroll
            for (int j = 0; j < 2; j++) v[j] = *(const float4*)&i2L[(jb + j) * 128 + k];
            #pragma unroll
            for (int kk = 0; kk < 4; kk++) {
                const float4 w = *(const float4*)&Win2[(size_t)(k + kk) * 128 + c0];
                #pragma unroll
                for (int j = 0; j < 2; j++) {
                    const float vv = ((const float*)&v[j])[kk];
                    acc[j].x = fmaf(vv, w.x, acc[j].x);
                    acc[j].y = fmaf(vv, w.y, acc[j].y);
                    acc[j].z = fmaf(vv, w.z, acc[j].z);
                    acc[j].w = fmaf(vv, w.w, acc[j].w);
                }
            }
        }
        for (int k = 0; k < 128; k += 4) {
            float4 v[2];
            #pragma unroll
            for (int j = 0; j < 2; j++) v[j] = *(const float4*)&o2L[(jb + j) * 128 + k];
            #pragma unroll
            for (int kk = 0; kk < 4; kk++) {
                const float4 w = *(const float4*)&Wout2[(size_t)(k + kk) * 128 + c0];
                #pragma unroll
                for (int j = 0; j < 2; j++) {
                    const float vv = ((const float*)&v[j])[kk];
                    acc[j].x = fmaf(vv, w.x, acc[j].x);
                    acc[j].y = fmaf(vv, w.y, acc[j].y);
                    acc[j].z = fmaf(vv, w.z, acc[j].z);
                    acc[j].w = fmaf(vv, w.w, acc[j].w);
                }
            }
        }
        #pragma unroll
        for (int j = 0; j < 2; j++) {
            float4 r;
            r.x = fmaxf(acc[j].x, 0.f); r.y = fmaxf(acc[j].y, 0.f);
            r.z = fmaxf(acc[j].z, 0.f); r.w = fmaxf(acc[j].w, 0.f);
            *(float4*)&n2L[(jb + j) * 128 + c0] = r;
        }
    }
    __syncthreads();

    // ---- per-graph n2 sums (fp32)
    if (t < 128) {
        if (gI[0] == gI[NPB - 1]) {
            float s = 0.f;
            #pragma unroll
            for (int j = 0; j < NPB; j++) s += n2L[j * 128 + t];
            atomicAdd(&gn2[(size_t)gI[0] * 128 + t], s);
        } else {
            int j = 0;
            while (j < NPB) {
                const int g = gI[j];
                int j2 = j;
                float s = 0.f;
                while (j2 < NPB && gI[j2] == g) { s += n2L[j2 * 128 + t]; j2++; }
                atomicAdd(&gn2[(size_t)g * 128 + t], s);
                j = j2;
            }
        }
    }
}

// ---------------------------------------------------------------------------
// Graph kernel: one block per graph. u1, u2, state_value, action MLP, output.
// ---------------------------------------------------------------------------
__global__ __launch_bounds__(256) void graph_kernel(
    const float* __restrict__ u,   // [B,64]
    const float* __restrict__ a,   // [B,8]
    const float* __restrict__ ge1, const float* __restrict__ ge2,
    const float* __restrict__ gecnt,
    const float* __restrict__ gn1, const float* __restrict__ gn2,
    const float* __restrict__ gncnt,
    const float* __restrict__ Wg1, const float* __restrict__ Wgn1,
    const float* __restrict__ Wge1, const float* __restrict__ bg1,
    const float* __restrict__ Wg2, const float* __restrict__ Wgn2,
    const float* __restrict__ Wge2, const float* __restrict__ bg2,
    const float* __restrict__ Wga, const float* __restrict__ bga,
    const float* __restrict__ Wa1, const float* __restrict__ ba1,
    const float* __restrict__ Wa2, const float* __restrict__ ba2,
    const float* __restrict__ Wa3, const float* __restrict__ ba3,
    float* __restrict__ out)
{
    const int g = blockIdx.x;
    const int t = threadIdx.x;
    __shared__ float uL[64], mn1[256], me1[256], mn2[128], me2[128];
    __shared__ float u1L[256], u2L[128], hL[144], h1L[256], h2L[256];
    __shared__ float red[4];

    const float ec = 1.f / fmaxf(gecnt[g], 1.f);
    const float nc = 1.f / fmaxf(gncnt[g], 1.f);
    if (t < 64) uL[t] = u[(size_t)g * 64 + t];
    mn1[t] = gn1[(size_t)g * 256 + t] * nc;
    me1[t] = ge1[(size_t)g * 256 + t] * ec;
    if (t < 128) {
        mn2[t] = gn2[(size_t)g * 128 + t] * nc;
        me2[t] = ge2[(size_t)g * 128 + t] * ec;
    }
    if (t >= 136 && t < 144) hL[t] = 0.f;
    __syncthreads();

    // u1 = relu(u@Wg1 + mn1@Wgn1 + me1@Wge1 + bg1)
    {
        float acc = bg1[t];
        for (int k = 0; k < 64; k++)  acc = fmaf(uL[k],  Wg1[(size_t)k * 256 + t], acc);
        for (int k = 0; k < 256; k++) acc = fmaf(mn1[k], Wgn1[(size_t)k * 256 + t], acc);
        for (int k = 0; k < 256; k++) acc = fmaf(me1[k], Wge1[(size_t)k * 256 + t], acc);
        u1L[t] = fmaxf(acc, 0.f);
    }
    __syncthreads();
    // u2 = relu(u1@Wg2 + mn2@Wgn2 + me2@Wge2 + bg2)
    if (t < 128) {
        float acc = bg2[t];
        for (int k = 0; k < 256; k++) acc = fmaf(u1L[k], Wg2[(size_t)k * 128 + t], acc);
        for (int k = 0; k < 128; k++) acc = fmaf(mn2[k], Wgn2[(size_t)k * 128 + t], acc);
        for (int k = 0; k < 128; k++) acc = fmaf(me2[k], Wge2[(size_t)k * 128 + t], acc);
        u2L[t] = fmaxf(acc, 0.f);
    }
    __syncthreads();
    // state_value + concat(a)
    if (t < 128) {
        float acc = bga[t];
        for (int k = 0; k < 128; k++) acc = fmaf(u2L[k], Wga[(size_t)k * 128 + t], acc);
        hL[t] = acc;
    }
    if (t >= 128 && t < 136) hL[t] = a[(size_t)g * 8 + (t - 128)];
    __syncthreads();
    // h1 = relu(h@Wa1+ba1)
    {
        float acc = ba1[t];
        for (int k = 0; k < 136; k++) acc = fmaf(hL[k], Wa1[(size_t)k * 256 + t], acc);
        h1L[t] = fmaxf(acc, 0.f);
    }
    __syncthreads();
    // h2 = relu(h1@Wa2+ba2)
    {
        float acc = ba2[t];
        for (int k = 0; k < 256; k++) acc = fmaf(h1L[k], Wa2[(size_t)k * 256 + t], acc);
        h2L[t] = fmaxf(acc, 0.f);
    }
    __syncthreads();
    // out = h2 @ Wa3 + ba3
    {
        float p = h2L[t] * Wa3[t];
        for (int off = 32; off > 0; off >>= 1) p += __shfl_down(p, off, 64);
        if ((t & 63) == 0) red[t >> 6] = p;
        __syncthreads();
        if (t == 0) out[g] = red[0] + red[1] + red[2] + red[3] + ba3[0];
    }
}

// ---------------------------------------------------------------------------
extern "C" void kernel_launch(void* const* d_in, const int* in_sizes, int n_in,
                              void* d_out, int out_size, void* d_ws, size_t ws_size,
                              hipStream_t stream) {
    const float* x          = (const float*)d_in[0];
    const float* e          = (const float*)d_in[1];
    const float* u          = (const float*)d_in[2];
    const float* a          = (const float*)d_in[3];
    const int*   senders    = (const int*)d_in[4];
    const int*   receivers  = (const int*)d_in[5];
    const int*   node_graph = (const int*)d_in[6];
    const int*   edge_graph = (const int*)d_in[7];
    const float* We1 = (const float*)d_in[8];  const float* be1 = (const float*)d_in[9];
    const float* Wn1 = (const float*)d_in[10]; const float* Win1 = (const float*)d_in[11];
    const float* Wout1 = (const float*)d_in[12]; const float* bn1 = (const float*)d_in[13];
    const float* Wg1 = (const float*)d_in[14]; const float* Wgn1 = (const float*)d_in[15];
    const float* Wge1 = (const float*)d_in[16]; const float* bg1 = (const float*)d_in[17];
    const float* We2 = (const float*)d_in[18]; const float* be2 = (const float*)d_in[19];
    const float* Wn2 = (const float*)d_in[20]; const float* Win2 = (const float*)d_in[21];
    const float* Wout2 = (const float*)d_in[22]; const float* bn2 = (const float*)d_in[23];
    const float* Wg2 = (const float*)d_in[24]; const float* Wgn2 = (const float*)d_in[25];
    const float* Wge2 = (const float*)d_in[26]; const float* bg2 = (const float*)d_in[27];
    const float* Wga = (const float*)d_in[28]; const float* bga = (const float*)d_in[29];
    const float* Wa1 = (const float*)d_in[30]; const float* ba1 = (const float*)d_in[31];
    const float* Wa2 = (const float*)d_in[32]; const float* ba2 = (const float*)d_in[33];
    const float* Wa3 = (const float*)d_in[34]; const float* ba3 = (const float*)d_in[35];

    // u64 packed u16x4 accumulators first (8B aligned), then fp32 accumulators
    unsigned long long* uw = (unsigned long long*)d_ws;
    unsigned long long* inc1u = uw;                       uw += (size_t)N_NODES * 64;
    unsigned long long* out1u = uw;                       uw += (size_t)N_NODES * 64;
    unsigned long long* inc2u = uw;                       uw += (size_t)N_NODES * 32;
    unsigned long long* out2u = uw;                       uw += (size_t)N_NODES * 32;
    float* fw = (float*)uw;
    float* rcnt = fw;  fw += N_NODES;
    float* scnt = fw;  fw += N_NODES;
    float* ge1  = fw;  fw += (size_t)N_GRAPHS * 256;
    float* ge2  = fw;  fw += (size_t)N_GRAPHS * 128;
    float* gecnt = fw; fw += N_GRAPHS;
    float* gn1  = fw;  fw += (size_t)N_GRAPHS * 256;
    float* gn2  = fw;  fw += (size_t)N_GRAPHS * 128;
    float* gncnt = fw; fw += N_GRAPHS;
    const size_t total_bytes = (char*)fw - (char*)d_ws;

    // zero all accumulators (harness poisons d_ws with 0xAA before each call)
    hipMemsetAsync(d_ws, 0, total_bytes, stream);

    edge_kernel<<<N_EDGES / EPB, 256, 0, stream>>>(
        e, senders, receivers, edge_graph, We1, be1, We2, be2,
        inc1u, out1u, inc2u, out2u, rcnt, scnt, ge1, ge2, gecnt);

    node_kernel<<<N_NODES / NPB, 256, 0, stream>>>(
        x, node_graph, inc1u, out1u, inc2u, out2u, rcnt, scnt,
        Wn1, Win1, Wout1, bn1, Wn2, Win2, Wout2, bn2, gn1, gn2, gncnt);

    graph_kernel<<<N_GRAPHS, 256, 0, stream>>>(
        u, a, ge1, ge2, gecnt, gn1, gn2, gncnt,
        Wg1, Wgn1, Wge1, bg1, Wg2, Wgn2, Wge2, bg2,
        Wga, bga, Wa1, ba1, Wa2, ba2, Wa3, ba3, (float*)d_out);
}

// Round 8
// 1323.953 us; speedup vs baseline: 1.8741x; 1.0966x over previous
//
#include <hip/hip_runtime.h>
#include <hip/hip_bf16.h>

// Problem constants (fixed by reference)
#define N_NODES 50000
#define N_EDGES 500000
#define N_GRAPHS 512

// ---------------------------------------------------------------------------
// Packed fixed-point atomics: FOUR non-negative fp32 channels packed as u16
// fixed point (scale 2^11) into one u64 atomicAdd. Valid: post-ReLU >= 0,
// per-node channel sums bounded ~12 -> max lane 24.6K << 65536 (no carry).
// ---------------------------------------------------------------------------
#define FXS16 2048.0f
#define FXI16 4.8828125e-4f  // 2^-11

__device__ __forceinline__ unsigned long long pk16x4(float4 v) {
    const unsigned long long a = (unsigned int)fmaf(v.x, FXS16, 0.5f);
    const unsigned long long b = (unsigned int)fmaf(v.y, FXS16, 0.5f);
    const unsigned long long c = (unsigned int)fmaf(v.z, FXS16, 0.5f);
    const unsigned long long d = (unsigned int)fmaf(v.w, FXS16, 0.5f);
    return a | (b << 16) | (c << 32) | (d << 48);
}

// MFMA fragment types (per cdna_hip_programming.md §3, compile-verified form)
typedef __attribute__((ext_vector_type(8))) short bf16x8;
typedef __attribute__((ext_vector_type(4))) float f32x4;

// ---------------------------------------------------------------------------
// Prep: Wt2[n*256+k] = bf16(We2[k*128+n])  (one-time per call, 32K elems)
// ---------------------------------------------------------------------------
__global__ __launch_bounds__(256) void prep_kernel(
    const float* __restrict__ We2, __hip_bfloat16* __restrict__ Wt2)
{
    const int i = blockIdx.x * 256 + threadIdx.x;   // 32768 total
    const int n = i >> 8, k = i & 255;
    Wt2[i] = __float2bfloat16(We2[(size_t)k * 128 + n]);
}

// ---------------------------------------------------------------------------
// Edge kernel (EPB=32, MFMA e2): e1=relu(e@We1+be1) via VALU fp32, stored
// bf16 in LDS (A-operand + scatter source); e2=relu(e1@We2+be2) via
// v_mfma_f32_16x16x32_bf16 (B = pre-transposed bf16 Wt2); u16x4 atomic
// scatter; per-graph fp32 sums. LDS ~38.3 KB -> 4 blocks/CU.
// ---------------------------------------------------------------------------
#define EPB 32      // edges per block; 500000 % 32 == 0 -> 15625 blocks
#define E1P 264     // e1B row stride (bf16): 256 + 8 pad (528 B, 16B-aligned)
#define E2P 132     // e2L row stride (f32): 128 + 4 pad (528 B, 16B-aligned)

__global__ __launch_bounds__(256) void edge_kernel(
    const float* __restrict__ e,          // [E,32]
    const int* __restrict__ senders,
    const int* __restrict__ receivers,
    const int* __restrict__ edge_graph,   // sorted
    const float* __restrict__ We1, const float* __restrict__ be1,   // [32,256],[256]
    const __hip_bfloat16* __restrict__ Wt2,                         // [128,256] bf16 (n-major)
    const float* __restrict__ be2,                                  // [128]
    unsigned long long* __restrict__ inc1u, unsigned long long* __restrict__ out1u, // [N,64]
    unsigned long long* __restrict__ inc2u, unsigned long long* __restrict__ out2u, // [N,32]
    float* __restrict__ rcnt, float* __restrict__ scnt,             // [N]
    float* __restrict__ ge1, float* __restrict__ ge2, float* __restrict__ gecnt)
{
    __shared__ float eL[EPB * 32];            // 4 KB
    __shared__ __hip_bfloat16 e1B[EPB * E1P]; // 16.5 KB
    __shared__ float e2L[EPB * E2P];          // 16.5 KB
    __shared__ int ridx[EPB], sidx[EPB], gidx[EPB];

    const int t = threadIdx.x;
    const long e0 = (long)blockIdx.x * EPB;

    for (int i = t; i < EPB * 32; i += 256) eL[i] = e[e0 * 32 + i];
    if (t < EPB) {
        ridx[t] = receivers[e0 + t];
        sidx[t] = senders[e0 + t];
        gidx[t] = edge_graph[e0 + t];
    }
    __syncthreads();

    // ---- e1 = relu(e @ We1 + be1), VALU fp32. thread: 4 ch, 8 edges -> bf16 LDS
    {
        const int c0 = (t & 63) * 4;
        const int jb = (t >> 6) * 8;
        float4 acc[8];
        const float4 b4 = *(const float4*)&be1[c0];
        #pragma unroll
        for (int j = 0; j < 8; j++) acc[j] = b4;
        for (int k = 0; k < 32; k += 4) {
            float4 v[8];
            #pragma unroll
            for (int j = 0; j < 8; j++) v[j] = *(const float4*)&eL[(jb + j) * 32 + k];
            #pragma unroll
            for (int kk = 0; kk < 4; kk++) {
                const float4 w = *(const float4*)&We1[(size_t)(k + kk) * 256 + c0];
                #pragma unroll
                for (int j = 0; j < 8; j++) {
                    const float vv = ((const float*)&v[j])[kk];
                    acc[j].x = fmaf(vv, w.x, acc[j].x);
                    acc[j].y = fmaf(vv, w.y, acc[j].y);
                    acc[j].z = fmaf(vv, w.z, acc[j].z);
                    acc[j].w = fmaf(vv, w.w, acc[j].w);
                }
            }
        }
        #pragma unroll
        for (int j = 0; j < 8; j++) {
            const float2 p0 = make_float2(fmaxf(acc[j].x, 0.f), fmaxf(acc[j].y, 0.f));
            const float2 p1 = make_float2(fmaxf(acc[j].z, 0.f), fmaxf(acc[j].w, 0.f));
            *(__hip_bfloat162*)&e1B[(jb + j) * E1P + c0]     = __float22bfloat162_rn(p0);
            *(__hip_bfloat162*)&e1B[(jb + j) * E1P + c0 + 2] = __float22bfloat162_rn(p1);
        }
    }
    __syncthreads();

    // ---- e2 = relu(e1 @ We2 + be2) via MFMA 16x16x32 bf16.
    // wave wv: n-tiles {2wv, 2wv+1}; both m-tiles; k-steps 8.
    {
        const int wv = t >> 6, ln = t & 63;
        const int r0 = ln & 15, q = ln >> 4;
        f32x4 acc[2][2] = {{{0.f,0.f,0.f,0.f},{0.f,0.f,0.f,0.f}},
                           {{0.f,0.f,0.f,0.f},{0.f,0.f,0.f,0.f}}};
        const int n0 = (2 * wv) * 16 + r0;     // B row for nt=0
        const int n1 = (2 * wv + 1) * 16 + r0; // B row for nt=1
        #pragma unroll
        for (int kb = 0; kb < 8; kb++) {
            const int k0 = kb * 32 + q * 8;
            const bf16x8 a0 = *(const bf16x8*)&e1B[(r0) * E1P + k0];
            const bf16x8 a1 = *(const bf16x8*)&e1B[(16 + r0) * E1P + k0];
            const bf16x8 b0 = *(const bf16x8*)&Wt2[(size_t)n0 * 256 + k0];
            const bf16x8 b1 = *(const bf16x8*)&Wt2[(size_t)n1 * 256 + k0];
            acc[0][0] = __builtin_amdgcn_mfma_f32_16x16x32_bf16(a0, b0, acc[0][0], 0, 0, 0);
            acc[0][1] = __builtin_amdgcn_mfma_f32_16x16x32_bf16(a0, b1, acc[0][1], 0, 0, 0);
            acc[1][0] = __builtin_amdgcn_mfma_f32_16x16x32_bf16(a1, b0, acc[1][0], 0, 0, 0);
            acc[1][1] = __builtin_amdgcn_mfma_f32_16x16x32_bf16(a1, b1, acc[1][1], 0, 0, 0);
        }
        // epilogue: D[m=q*4+r (in tile), n=r0 (in tile)] -> bias+relu -> e2L
        const float bz0 = be2[2 * wv * 16 + r0];
        const float bz1 = be2[(2 * wv + 1) * 16 + r0];
        #pragma unroll
        for (int mt = 0; mt < 2; mt++) {
            const int m = mt * 16 + q * 4;
            #pragma unroll
            for (int r = 0; r < 4; r++) {
                e2L[(m + r) * E2P + 2 * wv * 16 + r0]       = fmaxf(acc[mt][0][r] + bz0, 0.f);
                e2L[(m + r) * E2P + (2 * wv + 1) * 16 + r0] = fmaxf(acc[mt][1][r] + bz1, 0.f);
            }
        }
    }
    __syncthreads();

    // ---- scatter e1 (u64 = 4 channels from bf16): 2 dests x 64 words
    {
        const int w = t & 63;            // u64 word = channels 4w..4w+3
        const int ep = (t >> 6) & 1;     // edge parity
        unsigned long long* arr = (t < 128) ? inc1u : out1u;
        const int* idx = (t < 128) ? ridx : sidx;
        #pragma unroll
        for (int jj = 0; jj < EPB / 2; jj++) {
            const int j = jj * 2 + ep;
            const float2 v0 = __bfloat1622float2(*(const __hip_bfloat162*)&e1B[j * E1P + 4 * w]);
            const float2 v1 = __bfloat1622float2(*(const __hip_bfloat162*)&e1B[j * E1P + 4 * w + 2]);
            float4 v; v.x = v0.x; v.y = v0.y; v.z = v1.x; v.w = v1.y;
            atomicAdd(&arr[(size_t)idx[j] * 64 + w], pk16x4(v));
        }
    }
    // ---- scatter e2: 2 dests x 32 words x 4 edge-groups
    {
        const int w = t & 31;
        const int eq = (t >> 5) & 3;
        unsigned long long* arr = (t < 128) ? inc2u : out2u;
        const int* idx = (t < 128) ? ridx : sidx;
        #pragma unroll
        for (int jj = 0; jj < EPB / 4; jj++) {
            const int j = jj * 4 + eq;
            const float4 v = *(const float4*)&e2L[j * E2P + 4 * w];
            atomicAdd(&arr[(size_t)idx[j] * 32 + w], pk16x4(v));
        }
    }
    // ---- per-graph sums (edge_graph sorted), fp32
    if (gidx[0] == gidx[EPB - 1]) {
        const int g = gidx[0];
        float s = 0.f;
        #pragma unroll
        for (int j = 0; j < EPB; j++) s += __bfloat162float(e1B[j * E1P + t]);
        atomicAdd(&ge1[(size_t)g * 256 + t], s);
        if (t < 128) {
            float s2 = 0.f;
            #pragma unroll
            for (int j = 0; j < EPB; j++) s2 += e2L[j * E2P + t];
            atomicAdd(&ge2[(size_t)g * 128 + t], s2);
        }
        if (t == 0) atomicAdd(&gecnt[g], (float)EPB);
    } else {
        int j = 0;
        while (j < EPB) {
            const int g = gidx[j];
            int j2 = j;
            float s = 0.f;
            while (j2 < EPB && gidx[j2] == g) { s += __bfloat162float(e1B[j2 * E1P + t]); j2++; }
            atomicAdd(&ge1[(size_t)g * 256 + t], s);
            if (t < 128) {
                float s2 = 0.f;
                for (int jj = j; jj < j2; jj++) s2 += e2L[jj * E2P + t];
                atomicAdd(&ge2[(size_t)g * 128 + t], s2);
            }
            if (t == 0) atomicAdd(&gecnt[g], (float)(j2 - j));
            j = j2;
        }
    }
    if (t < EPB) {
        atomicAdd(&rcnt[ridx[t]], 1.f);
        atomicAdd(&scnt[sidx[t]], 1.f);
    }
}

// ---------------------------------------------------------------------------
// Node kernel (R7-proven, unchanged)
// ---------------------------------------------------------------------------
#define NPB 16  // nodes per block; 50000 % 16 == 0

__global__ __launch_bounds__(256) void node_kernel(
    const float* __restrict__ x,            // [N,64]
    const int* __restrict__ node_graph,     // sorted
    const unsigned long long* __restrict__ inc1u, const unsigned long long* __restrict__ out1u,
    const unsigned long long* __restrict__ inc2u, const unsigned long long* __restrict__ out2u,
    const float* __restrict__ rcnt, const float* __restrict__ scnt,
    const float* __restrict__ Wn1, const float* __restrict__ Win1,
    const float* __restrict__ Wout1, const float* __restrict__ bn1,
    const float* __restrict__ Wn2, const float* __restrict__ Win2,
    const float* __restrict__ Wout2, const float* __restrict__ bn2,
    float* __restrict__ gn1, float* __restrict__ gn2, float* __restrict__ gncnt)
{
    __shared__ float xL[NPB * 64];     // 4 KB
    __shared__ float i1L[NPB * 256];   // 16 KB
    __shared__ float o1L[NPB * 256];   // 16 KB
    __shared__ float i2L[NPB * 128];   // 8 KB
    __shared__ float o2L[NPB * 128];   // 8 KB
    __shared__ float n1L[NPB * 256];   // 16 KB
    __shared__ float n2L[NPB * 128];   // 8 KB
    __shared__ int gI[NPB];
    __shared__ float rrcp[NPB], srcp[NPB];

    const int t = threadIdx.x;
    const long n0 = (long)blockIdx.x * NPB;

    for (int i = t; i < NPB * 16; i += 256)
        *(float4*)&xL[i * 4] = *(const float4*)&x[n0 * 64 + i * 4];
    if (t < NPB) {
        gI[t] = node_graph[n0 + t];
        rrcp[t] = 1.f / fmaxf(rcnt[n0 + t], 1.f);
        srcp[t] = 1.f / fmaxf(scnt[n0 + t], 1.f);
    }
    __syncthreads();
    // decode u16x4 fixed-point accumulators -> scaled means in LDS
    for (int i = t; i < NPB * 64; i += 256) {
        const int j = i >> 6, w = i & 63;
        const size_t n = (size_t)(n0 + j);
        const unsigned long long av = inc1u[n * 64 + w];
        const unsigned long long bv = out1u[n * 64 + w];
        const float rr = rrcp[j] * FXI16, sr = srcp[j] * FXI16;
        float4 af, bf;
        af.x = (float)(unsigned int)(av & 0xFFFF) * rr;
        af.y = (float)(unsigned int)((av >> 16) & 0xFFFF) * rr;
        af.z = (float)(unsigned int)((av >> 32) & 0xFFFF) * rr;
        af.w = (float)(unsigned int)(av >> 48) * rr;
        bf.x = (float)(unsigned int)(bv & 0xFFFF) * sr;
        bf.y = (float)(unsigned int)((bv >> 16) & 0xFFFF) * sr;
        bf.z = (float)(unsigned int)((bv >> 32) & 0xFFFF) * sr;
        bf.w = (float)(unsigned int)(bv >> 48) * sr;
        *(float4*)&i1L[j * 256 + 4 * w] = af;
        *(float4*)&o1L[j * 256 + 4 * w] = bf;
    }
    for (int i = t; i < NPB * 32; i += 256) {
        const int j = i >> 5, w = i & 31;
        const size_t n = (size_t)(n0 + j);
        const unsigned long long av = inc2u[n * 32 + w];
        const unsigned long long bv = out2u[n * 32 + w];
        const float rr = rrcp[j] * FXI16, sr = srcp[j] * FXI16;
        float4 af, bf;
        af.x = (float)(unsigned int)(av & 0xFFFF) * rr;
        af.y = (float)(unsigned int)((av >> 16) & 0xFFFF) * rr;
        af.z = (float)(unsigned int)((av >> 32) & 0xFFFF) * rr;
        af.w = (float)(unsigned int)(av >> 48) * rr;
        bf.x = (float)(unsigned int)(bv & 0xFFFF) * sr;
        bf.y = (float)(unsigned int)((bv >> 16) & 0xFFFF) * sr;
        bf.z = (float)(unsigned int)((bv >> 32) & 0xFFFF) * sr;
        bf.w = (float)(unsigned int)(bv >> 48) * sr;
        *(float4*)&i2L[j * 128 + 4 * w] = af;
        *(float4*)&o2L[j * 128 + 4 * w] = bf;
    }
    __syncthreads();

    // ---- n1: thread = 4 channels, 4 nodes
    {
        const int c0 = (t & 63) * 4;
        const int jb = (t >> 6) * 4;
        float4 acc[4];
        const float4 b4 = *(const float4*)&bn1[c0];
        #pragma unroll
        for (int j = 0; j < 4; j++) acc[j] = b4;
        for (int k = 0; k < 64; k += 4) {
            float4 v[4];
            #pragma unroll
            for (int j = 0; j < 4; j++) v[j] = *(const float4*)&xL[(jb + j) * 64 + k];
            #pragma unroll
            for (int kk = 0; kk < 4; kk++) {
                const float4 w = *(const float4*)&Wn1[(size_t)(k + kk) * 256 + c0];
                #pragma unroll
                for (int j = 0; j < 4; j++) {
                    const float vv = ((const float*)&v[j])[kk];
                    acc[j].x = fmaf(vv, w.x, acc[j].x);
                    acc[j].y = fmaf(vv, w.y, acc[j].y);
                    acc[j].z = fmaf(vv, w.z, acc[j].z);
                    acc[j].w = fmaf(vv, w.w, acc[j].w);
                }
            }
        }
        for (int k = 0; k < 256; k += 4) {
            float4 v[4];
            #pragma unroll
            for (int j = 0; j < 4; j++) v[j] = *(const float4*)&i1L[(jb + j) * 256 + k];
            #pragma unroll
            for (int kk = 0; kk < 4; kk++) {
                const float4 w = *(const float4*)&Win1[(size_t)(k + kk) * 256 + c0];
                #pragma unroll
                for (int j = 0; j < 4; j++) {
                    const float vv = ((const float*)&v[j])[kk];
                    acc[j].x = fmaf(vv, w.x, acc[j].x);
                    acc[j].y = fmaf(vv, w.y, acc[j].y);
                    acc[j].z = fmaf(vv, w.z, acc[j].z);
                    acc[j].w = fmaf(vv, w.w, acc[j].w);
                }
            }
        }
        for (int k = 0; k < 256; k += 4) {
            float4 v[4];
            #pragma unroll
            for (int j = 0; j < 4; j++) v[j] = *(const float4*)&o1L[(jb + j) * 256 + k];
            #pragma unroll
            for (int kk = 0; kk < 4; kk++) {
                const float4 w = *(const float4*)&Wout1[(size_t)(k + kk) * 256 + c0];
                #pragma unroll
                for (int j = 0; j < 4; j++) {
                    const float vv = ((const float*)&v[j])[kk];
                    acc[j].x = fmaf(vv, w.x, acc[j].x);
                    acc[j].y = fmaf(vv, w.y, acc[j].y);
                    acc[j].z = fmaf(vv, w.z, acc[j].z);
                    acc[j].w = fmaf(vv, w.w, acc[j].w);
                }
            }
        }
        #pragma unroll
        for (int j = 0; j < 4; j++) {
            float4 r;
            r.x = fmaxf(acc[j].x, 0.f); r.y = fmaxf(acc[j].y, 0.f);
            r.z = fmaxf(acc[j].z, 0.f); r.w = fmaxf(acc[j].w, 0.f);
            *(float4*)&n1L[(jb + j) * 256 + c0] = r;
        }
    }
    __syncthreads();

    // ---- per-graph n1 sums (fp32, sorted-run aggregation)
    if (gI[0] == gI[NPB - 1]) {
        float s = 0.f;
        #pragma unroll
        for (int j = 0; j < NPB; j++) s += n1L[j * 256 + t];
        atomicAdd(&gn1[(size_t)gI[0] * 256 + t], s);
        if (t == 0) atomicAdd(&gncnt[gI[0]], (float)NPB);
    } else {
        int j = 0;
        while (j < NPB) {
            const int g = gI[j];
            int j2 = j;
            float s = 0.f;
            while (j2 < NPB && gI[j2] == g) { s += n1L[j2 * 256 + t]; j2++; }
            atomicAdd(&gn1[(size_t)g * 256 + t], s);
            if (t == 0) atomicAdd(&gncnt[g], (float)(j2 - j));
            j = j2;
        }
    }

    // ---- n2: thread = 4 channels, 2 nodes
    {
        const int c0 = (t & 31) * 4;
        const int jb = (t >> 5) * 2;
        float4 acc[2];
        const float4 b4 = *(const float4*)&bn2[c0];
        #pragma unroll
        for (int j = 0; j < 2; j++) acc[j] = b4;
        for (int k = 0; k < 256; k += 4) {
            float4 v[2];
            #pragma unroll
            for (int j = 0; j < 2; j++) v[j] = *(const float4*)&n1L[(jb + j) * 256 + k];
            #pragma unroll
            for (int kk = 0; kk < 4; kk++) {
                const float4 w = *(const float4*)&Wn2[(size_t)(k + kk) * 128 + c0];
                #pragma unroll
                for (int j = 0; j < 2; j++) {
                    const float vv = ((const float*)&v[j])[kk];
                    acc[j].x = fmaf(vv, w.x, acc[j].x);
                    acc[j].y = fmaf(vv, w.y, acc[j].y);
                    acc[j].z = fmaf(vv, w.z, acc[j].z);
                    acc[j].w = fmaf(vv, w.w, acc[j].w);
                }
            }
        }
        for (int k = 0; k < 128; k += 4) {
            float4 v[2];
            #pragma unroll
            for (int j = 0; j < 2; j++) v[j] = *(const float4*)&i2L[(jb + j) * 128 + k];
            #pragma unroll
            for (int kk = 0; kk < 4; kk++) {
                const float4 w = *(const float4*)&Win2[(size_t)(k + kk) * 128 + c0];
                #pragma unroll
                for (int j = 0; j < 2; j++) {
                    const float vv = ((const float*)&v[j])[kk];
                    acc[j].x = fmaf(vv, w.x, acc[j].x);
                    acc[j].y = fmaf(vv, w.y, acc[j].y);
                    acc[j].z = fmaf(vv, w.z, acc[j].z);
                    acc[j].w = fmaf(vv, w.w, acc[j].w);
                }
            }
        }
        for (int k = 0; k < 128; k += 4) {
            float4 v[2];
            #pragma unroll
            for (int j = 0; j < 2; j++) v[j] = *(const float4*)&o2L[(jb + j) * 128 + k];
            #pragma unroll
            for (int kk = 0; kk < 4; kk++) {
                const float4 w = *(const float4*)&Wout2[(size_t)(k + kk) * 128 + c0];
                #pragma unroll
                for (int j = 0; j < 2; j++) {
                    const float vv = ((const float*)&v[j])[kk];
                    acc[j].x = fmaf(vv, w.x, acc[j].x);
                    acc[j].y = fmaf(vv, w.y, acc[j].y);
                    acc[j].z = fmaf(vv, w.z, acc[j].z);
                    acc[j].w = fmaf(vv, w.w, acc[j].w);
                }
            }
        }
        #pragma unroll
        for (int j = 0; j < 2; j++) {
            float4 r;
            r.x = fmaxf(acc[j].x, 0.f); r.y = fmaxf(acc[j].y, 0.f);
            r.z = fmaxf(acc[j].z, 0.f); r.w = fmaxf(acc[j].w, 0.f);
            *(float4*)&n2L[(jb + j) * 128 + c0] = r;
        }
    }
    __syncthreads();

    // ---- per-graph n2 sums (fp32)
    if (t < 128) {
        if (gI[0] == gI[NPB - 1]) {
            float s = 0.f;
            #pragma unroll
            for (int j = 0; j < NPB; j++) s += n2L[j * 128 + t];
            atomicAdd(&gn2[(size_t)gI[0] * 128 + t], s);
        } else {
            int j = 0;
            while (j < NPB) {
                const int g = gI[j];
                int j2 = j;
                float s = 0.f;
                while (j2 < NPB && gI[j2] == g) { s += n2L[j2 * 128 + t]; j2++; }
                atomicAdd(&gn2[(size_t)g * 128 + t], s);
                j = j2;
            }
        }
    }
}

// ---------------------------------------------------------------------------
// Graph kernel: one block per graph. u1, u2, state_value, action MLP, output.
// ---------------------------------------------------------------------------
__global__ __launch_bounds__(256) void graph_kernel(
    const float* __restrict__ u,   // [B,64]
    const float* __restrict__ a,   // [B,8]
    const float* __restrict__ ge1, const float* __restrict__ ge2,
    const float* __restrict__ gecnt,
    const float* __restrict__ gn1, const float* __restrict__ gn2,
    const float* __restrict__ gncnt,
    const float* __restrict__ Wg1, const float* __restrict__ Wgn1,
    const float* __restrict__ Wge1, const float* __restrict__ bg1,
    const float* __restrict__ Wg2, const float* __restrict__ Wgn2,
    const float* __restrict__ Wge2, const float* __restrict__ bg2,
    const float* __restrict__ Wga, const float* __restrict__ bga,
    const float* __restrict__ Wa1, const float* __restrict__ ba1,
    const float* __restrict__ Wa2, const float* __restrict__ ba2,
    const float* __restrict__ Wa3, const float* __restrict__ ba3,
    float* __restrict__ out)
{
    const int g = blockIdx.x;
    const int t = threadIdx.x;
    __shared__ float uL[64], mn1[256], me1[256], mn2[128], me2[128];
    __shared__ float u1L[256], u2L[128], hL[144], h1L[256], h2L[256];
    __shared__ float red[4];

    const float ec = 1.f / fmaxf(gecnt[g], 1.f);
    const float nc = 1.f / fmaxf(gncnt[g], 1.f);
    if (t < 64) uL[t] = u[(size_t)g * 64 + t];
    mn1[t] = gn1[(size_t)g * 256 + t] * nc;
    me1[t] = ge1[(size_t)g * 256 + t] * ec;
    if (t < 128) {
        mn2[t] = gn2[(size_t)g * 128 + t] * nc;
        me2[t] = ge2[(size_t)g * 128 + t] * ec;
    }
    if (t >= 136 && t < 144) hL[t] = 0.f;
    __syncthreads();

    // u1 = relu(u@Wg1 + mn1@Wgn1 + me1@Wge1 + bg1)
    {
        float acc = bg1[t];
        for (int k = 0; k < 64; k++)  acc = fmaf(uL[k],  Wg1[(size_t)k * 256 + t], acc);
        for (int k = 0; k < 256; k++) acc = fmaf(mn1[k], Wgn1[(size_t)k * 256 + t], acc);
        for (int k = 0; k < 256; k++) acc = fmaf(me1[k], Wge1[(size_t)k * 256 + t], acc);
        u1L[t] = fmaxf(acc, 0.f);
    }
    __syncthreads();
    // u2 = relu(u1@Wg2 + mn2@Wgn2 + me2@Wge2 + bg2)
    if (t < 128) {
        float acc = bg2[t];
        for (int k = 0; k < 256; k++) acc = fmaf(u1L[k], Wg2[(size_t)k * 128 + t], acc);
        for (int k = 0; k < 128; k++) acc = fmaf(mn2[k], Wgn2[(size_t)k * 128 + t], acc);
        for (int k = 0; k < 128; k++) acc = fmaf(me2[k], Wge2[(size_t)k * 128 + t], acc);
        u2L[t] = fmaxf(acc, 0.f);
    }
    __syncthreads();
    // state_value + concat(a)
    if (t < 128) {
        float acc = bga[t];
        for (int k = 0; k < 128; k++) acc = fmaf(u2L[k], Wga[(size_t)k * 128 + t], acc);
        hL[t] = acc;
    }
    if (t >= 128 && t < 136) hL[t] = a[(size_t)g * 8 + (t - 128)];
    __syncthreads();
    // h1 = relu(h@Wa1+ba1)
    {
        float acc = ba1[t];
        for (int k = 0; k < 136; k++) acc = fmaf(hL[k], Wa1[(size_t)k * 256 + t], acc);
        h1L[t] = fmaxf(acc, 0.f);
    }
    __syncthreads();
    // h2 = relu(h1@Wa2+ba2)
    {
        float acc = ba2[t];
        for (int k = 0; k < 256; k++) acc = fmaf(h1L[k], Wa2[(size_t)k * 256 + t], acc);
        h2L[t] = fmaxf(acc, 0.f);
    }
    __syncthreads();
    // out = h2 @ Wa3 + ba3
    {
        float p = h2L[t] * Wa3[t];
        for (int off = 32; off > 0; off >>= 1) p += __shfl_down(p, off, 64);
        if ((t & 63) == 0) red[t >> 6] = p;
        __syncthreads();
        if (t == 0) out[g] = red[0] + red[1] + red[2] + red[3] + ba3[0];
    }
}

// ---------------------------------------------------------------------------
extern "C" void kernel_launch(void* const* d_in, const int* in_sizes, int n_in,
                              void* d_out, int out_size, void* d_ws, size_t ws_size,
                              hipStream_t stream) {
    const float* x          = (const float*)d_in[0];
    const float* e          = (const float*)d_in[1];
    const float* u          = (const float*)d_in[2];
    const float* a          = (const float*)d_in[3];
    const int*   senders    = (const int*)d_in[4];
    const int*   receivers  = (const int*)d_in[5];
    const int*   node_graph = (const int*)d_in[6];
    const int*   edge_graph = (const int*)d_in[7];
    const float* We1 = (const float*)d_in[8];  const float* be1 = (const float*)d_in[9];
    const float* Wn1 = (const float*)d_in[10]; const float* Win1 = (const float*)d_in[11];
    const float* Wout1 = (const float*)d_in[12]; const float* bn1 = (const float*)d_in[13];
    const float* Wg1 = (const float*)d_in[14]; const float* Wgn1 = (const float*)d_in[15];
    const float* Wge1 = (const float*)d_in[16]; const float* bg1 = (const float*)d_in[17];
    const float* We2 = (const float*)d_in[18]; const float* be2 = (const float*)d_in[19];
    const float* Wn2 = (const float*)d_in[20]; const float* Win2 = (const float*)d_in[21];
    const float* Wout2 = (const float*)d_in[22]; const float* bn2 = (const float*)d_in[23];
    const float* Wg2 = (const float*)d_in[24]; const float* Wgn2 = (const float*)d_in[25];
    const float* Wge2 = (const float*)d_in[26]; const float* bg2 = (const float*)d_in[27];
    const float* Wga = (const float*)d_in[28]; const float* bga = (const float*)d_in[29];
    const float* Wa1 = (const float*)d_in[30]; const float* ba1 = (const float*)d_in[31];
    const float* Wa2 = (const float*)d_in[32]; const float* ba2 = (const float*)d_in[33];
    const float* Wa3 = (const float*)d_in[34]; const float* ba3 = (const float*)d_in[35];

    // u64 packed u16x4 accumulators first (8B aligned), then fp32, then Wt2
    unsigned long long* uw = (unsigned long long*)d_ws;
    unsigned long long* inc1u = uw;                       uw += (size_t)N_NODES * 64;
    unsigned long long* out1u = uw;                       uw += (size_t)N_NODES * 64;
    unsigned long long* inc2u = uw;                       uw += (size_t)N_NODES * 32;
    unsigned long long* out2u = uw;                       uw += (size_t)N_NODES * 32;
    float* fw = (float*)uw;
    float* rcnt = fw;  fw += N_NODES;
    float* scnt = fw;  fw += N_NODES;
    float* ge1  = fw;  fw += (size_t)N_GRAPHS * 256;
    float* ge2  = fw;  fw += (size_t)N_GRAPHS * 128;
    float* gecnt = fw; fw += N_GRAPHS;
    float* gn1  = fw;  fw += (size_t)N_GRAPHS * 256;
    float* gn2  = fw;  fw += (size_t)N_GRAPHS * 128;
    float* gncnt = fw; fw += N_GRAPHS;
    const size_t total_bytes = (char*)fw - (char*)d_ws;
    __hip_bfloat16* Wt2 = (__hip_bfloat16*)fw;  // 128*256 bf16 = 64 KB (not zeroed)

    // zero accumulators (harness poisons d_ws with 0xAA before each call)
    hipMemsetAsync(d_ws, 0, total_bytes, stream);

    prep_kernel<<<128, 256, 0, stream>>>(We2, Wt2);

    edge_kernel<<<N_EDGES / EPB, 256, 0, stream>>>(
        e, senders, receivers, edge_graph, We1, be1, Wt2, be2,
        inc1u, out1u, inc2u, out2u, rcnt, scnt, ge1, ge2, gecnt);

    node_kernel<<<N_NODES / NPB, 256, 0, stream>>>(
        x, node_graph, inc1u, out1u, inc2u, out2u, rcnt, scnt,
        Wn1, Win1, Wout1, bn1, Wn2, Win2, Wout2, bn2, gn1, gn2, gncnt);

    graph_kernel<<<N_GRAPHS, 256, 0, stream>>>(
        u, a, ge1, ge2, gecnt, gn1, gn2, gncnt,
        Wg1, Wgn1, Wge1, bg1, Wg2, Wgn2, Wge2, bg2,
        Wga, bga, Wa1, ba1, Wa2, ba2, Wa3, ba3, (float*)d_out);
}

// Round 9
// 1027.386 us; speedup vs baseline: 2.4150x; 1.2887x over previous
//
#include <hip/hip_runtime.h>
#include <hip/hip_bf16.h>

// Problem constants (fixed by reference)
#define N_NODES 50000
#define N_EDGES 500000
#define N_GRAPHS 512

// ---------------------------------------------------------------------------
// Packed fixed-point atomics: FOUR non-negative fp32 channels packed as u16
// fixed point (scale 2^11) into one u64 atomicAdd. Valid: post-ReLU >= 0,
// per-node channel sums bounded ~12 -> max lane 24.6K << 65536 (no carry).
// ---------------------------------------------------------------------------
#define FXS16 2048.0f
#define FXI16 4.8828125e-4f  // 2^-11

__device__ __forceinline__ unsigned long long pk16x4(float4 v) {
    const unsigned long long a = (unsigned int)fmaf(v.x, FXS16, 0.5f);
    const unsigned long long b = (unsigned int)fmaf(v.y, FXS16, 0.5f);
    const unsigned long long c = (unsigned int)fmaf(v.z, FXS16, 0.5f);
    const unsigned long long d = (unsigned int)fmaf(v.w, FXS16, 0.5f);
    return a | (b << 16) | (c << 32) | (d << 48);
}

// MFMA fragment types
typedef __attribute__((ext_vector_type(8))) short bf16x8;
typedef __attribute__((ext_vector_type(4))) float f32x4;

// ---------------------------------------------------------------------------
// Prep: transpose all weights needed as MFMA B-operands to bf16 n-major:
// dst[n*K+k] = bf16(src[k*N+n]). One fat kernel, block ranges per weight.
// ---------------------------------------------------------------------------
__global__ __launch_bounds__(256) void prep_kernel(
    const float* __restrict__ We2,  const float* __restrict__ Wn1,
    const float* __restrict__ Win1, const float* __restrict__ Wout1,
    const float* __restrict__ Wn2,  const float* __restrict__ Win2,
    const float* __restrict__ Wout2,
    __hip_bfloat16* __restrict__ Wt2,  __hip_bfloat16* __restrict__ Wn1t,
    __hip_bfloat16* __restrict__ Win1t,__hip_bfloat16* __restrict__ Wout1t,
    __hip_bfloat16* __restrict__ Wn2t, __hip_bfloat16* __restrict__ Win2t,
    __hip_bfloat16* __restrict__ Wout2t)
{
    const int b = blockIdx.x, t = threadIdx.x;
    const float* src; __hip_bfloat16* dst; int K, N, base;
    if (b < 128)      { src = We2;   dst = Wt2;    K = 256; N = 128; base = 0; }
    else if (b < 192) { src = Wn1;   dst = Wn1t;   K = 64;  N = 256; base = 128; }
    else if (b < 448) { src = Win1;  dst = Win1t;  K = 256; N = 256; base = 192; }
    else if (b < 704) { src = Wout1; dst = Wout1t; K = 256; N = 256; base = 448; }
    else if (b < 832) { src = Wn2;   dst = Wn2t;   K = 256; N = 128; base = 704; }
    else if (b < 896) { src = Win2;  dst = Win2t;  K = 128; N = 128; base = 832; }
    else              { src = Wout2; dst = Wout2t; K = 128; N = 128; base = 896; }
    const int i = (b - base) * 256 + t;
    const int n = i / K, k = i - n * K;
    dst[i] = __float2bfloat16(src[(size_t)k * N + n]);
}

// ---------------------------------------------------------------------------
// Edge kernel (R8-proven, unchanged): e1 VALU fp32 -> bf16 LDS; e2 via MFMA;
// u16x4 atomic scatter; per-graph fp32 sums.
// ---------------------------------------------------------------------------
#define EPB 32
#define E1P 264
#define E2P 132

__global__ __launch_bounds__(256) void edge_kernel(
    const float* __restrict__ e,
    const int* __restrict__ senders,
    const int* __restrict__ receivers,
    const int* __restrict__ edge_graph,
    const float* __restrict__ We1, const float* __restrict__ be1,
    const __hip_bfloat16* __restrict__ Wt2,
    const float* __restrict__ be2,
    unsigned long long* __restrict__ inc1u, unsigned long long* __restrict__ out1u,
    unsigned long long* __restrict__ inc2u, unsigned long long* __restrict__ out2u,
    float* __restrict__ rcnt, float* __restrict__ scnt,
    float* __restrict__ ge1, float* __restrict__ ge2, float* __restrict__ gecnt)
{
    __shared__ float eL[EPB * 32];
    __shared__ __hip_bfloat16 e1B[EPB * E1P];
    __shared__ float e2L[EPB * E2P];
    __shared__ int ridx[EPB], sidx[EPB], gidx[EPB];

    const int t = threadIdx.x;
    const long e0 = (long)blockIdx.x * EPB;

    for (int i = t; i < EPB * 32; i += 256) eL[i] = e[e0 * 32 + i];
    if (t < EPB) {
        ridx[t] = receivers[e0 + t];
        sidx[t] = senders[e0 + t];
        gidx[t] = edge_graph[e0 + t];
    }
    __syncthreads();

    {
        const int c0 = (t & 63) * 4;
        const int jb = (t >> 6) * 8;
        float4 acc[8];
        const float4 b4 = *(const float4*)&be1[c0];
        #pragma unroll
        for (int j = 0; j < 8; j++) acc[j] = b4;
        for (int k = 0; k < 32; k += 4) {
            float4 v[8];
            #pragma unroll
            for (int j = 0; j < 8; j++) v[j] = *(const float4*)&eL[(jb + j) * 32 + k];
            #pragma unroll
            for (int kk = 0; kk < 4; kk++) {
                const float4 w = *(const float4*)&We1[(size_t)(k + kk) * 256 + c0];
                #pragma unroll
                for (int j = 0; j < 8; j++) {
                    const float vv = ((const float*)&v[j])[kk];
                    acc[j].x = fmaf(vv, w.x, acc[j].x);
                    acc[j].y = fmaf(vv, w.y, acc[j].y);
                    acc[j].z = fmaf(vv, w.z, acc[j].z);
                    acc[j].w = fmaf(vv, w.w, acc[j].w);
                }
            }
        }
        #pragma unroll
        for (int j = 0; j < 8; j++) {
            const float2 p0 = make_float2(fmaxf(acc[j].x, 0.f), fmaxf(acc[j].y, 0.f));
            const float2 p1 = make_float2(fmaxf(acc[j].z, 0.f), fmaxf(acc[j].w, 0.f));
            *(__hip_bfloat162*)&e1B[(jb + j) * E1P + c0]     = __float22bfloat162_rn(p0);
            *(__hip_bfloat162*)&e1B[(jb + j) * E1P + c0 + 2] = __float22bfloat162_rn(p1);
        }
    }
    __syncthreads();

    {
        const int wv = t >> 6, ln = t & 63;
        const int r0 = ln & 15, q = ln >> 4;
        f32x4 acc[2][2] = {{{0.f,0.f,0.f,0.f},{0.f,0.f,0.f,0.f}},
                           {{0.f,0.f,0.f,0.f},{0.f,0.f,0.f,0.f}}};
        const int n0 = (2 * wv) * 16 + r0;
        const int n1 = (2 * wv + 1) * 16 + r0;
        #pragma unroll
        for (int kb = 0; kb < 8; kb++) {
            const int k0 = kb * 32 + q * 8;
            const bf16x8 a0 = *(const bf16x8*)&e1B[(r0) * E1P + k0];
            const bf16x8 a1 = *(const bf16x8*)&e1B[(16 + r0) * E1P + k0];
            const bf16x8 b0 = *(const bf16x8*)&Wt2[(size_t)n0 * 256 + k0];
            const bf16x8 b1 = *(const bf16x8*)&Wt2[(size_t)n1 * 256 + k0];
            acc[0][0] = __builtin_amdgcn_mfma_f32_16x16x32_bf16(a0, b0, acc[0][0], 0, 0, 0);
            acc[0][1] = __builtin_amdgcn_mfma_f32_16x16x32_bf16(a0, b1, acc[0][1], 0, 0, 0);
            acc[1][0] = __builtin_amdgcn_mfma_f32_16x16x32_bf16(a1, b0, acc[1][0], 0, 0, 0);
            acc[1][1] = __builtin_amdgcn_mfma_f32_16x16x32_bf16(a1, b1, acc[1][1], 0, 0, 0);
        }
        const float bz0 = be2[2 * wv * 16 + r0];
        const float bz1 = be2[(2 * wv + 1) * 16 + r0];
        #pragma unroll
        for (int mt = 0; mt < 2; mt++) {
            const int m = mt * 16 + q * 4;
            #pragma unroll
            for (int r = 0; r < 4; r++) {
                e2L[(m + r) * E2P + 2 * wv * 16 + r0]       = fmaxf(acc[mt][0][r] + bz0, 0.f);
                e2L[(m + r) * E2P + (2 * wv + 1) * 16 + r0] = fmaxf(acc[mt][1][r] + bz1, 0.f);
            }
        }
    }
    __syncthreads();

    {
        const int w = t & 63;
        const int ep = (t >> 6) & 1;
        unsigned long long* arr = (t < 128) ? inc1u : out1u;
        const int* idx = (t < 128) ? ridx : sidx;
        #pragma unroll
        for (int jj = 0; jj < EPB / 2; jj++) {
            const int j = jj * 2 + ep;
            const float2 v0 = __bfloat1622float2(*(const __hip_bfloat162*)&e1B[j * E1P + 4 * w]);
            const float2 v1 = __bfloat1622float2(*(const __hip_bfloat162*)&e1B[j * E1P + 4 * w + 2]);
            float4 v; v.x = v0.x; v.y = v0.y; v.z = v1.x; v.w = v1.y;
            atomicAdd(&arr[(size_t)idx[j] * 64 + w], pk16x4(v));
        }
    }
    {
        const int w = t & 31;
        const int eq = (t >> 5) & 3;
        unsigned long long* arr = (t < 128) ? inc2u : out2u;
        const int* idx = (t < 128) ? ridx : sidx;
        #pragma unroll
        for (int jj = 0; jj < EPB / 4; jj++) {
            const int j = jj * 4 + eq;
            const float4 v = *(const float4*)&e2L[j * E2P + 4 * w];
            atomicAdd(&arr[(size_t)idx[j] * 32 + w], pk16x4(v));
        }
    }
    if (gidx[0] == gidx[EPB - 1]) {
        const int g = gidx[0];
        float s = 0.f;
        #pragma unroll
        for (int j = 0; j < EPB; j++) s += __bfloat162float(e1B[j * E1P + t]);
        atomicAdd(&ge1[(size_t)g * 256 + t], s);
        if (t < 128) {
            float s2 = 0.f;
            #pragma unroll
            for (int j = 0; j < EPB; j++) s2 += e2L[j * E2P + t];
            atomicAdd(&ge2[(size_t)g * 128 + t], s2);
        }
        if (t == 0) atomicAdd(&gecnt[g], (float)EPB);
    } else {
        int j = 0;
        while (j < EPB) {
            const int g = gidx[j];
            int j2 = j;
            float s = 0.f;
            while (j2 < EPB && gidx[j2] == g) { s += __bfloat162float(e1B[j2 * E1P + t]); j2++; }
            atomicAdd(&ge1[(size_t)g * 256 + t], s);
            if (t < 128) {
                float s2 = 0.f;
                for (int jj = j; jj < j2; jj++) s2 += e2L[jj * E2P + t];
                atomicAdd(&ge2[(size_t)g * 128 + t], s2);
            }
            if (t == 0) atomicAdd(&gecnt[g], (float)(j2 - j));
            j = j2;
        }
    }
    if (t < EPB) {
        atomicAdd(&rcnt[ridx[t]], 1.f);
        atomicAdd(&scnt[sidx[t]], 1.f);
    }
}

// ---------------------------------------------------------------------------
// Node kernel (R9: MFMA): decode u16x4 accumulators -> bf16 means in LDS;
// n1 = relu(x@Wn1 + i1@Win1 + o1@Wout1 + bn1) via MFMA (M=16, N=256, 18 ksteps);
// n2 = relu(n1@Wn2 + i2@Win2 + o2@Wout2 + bn2) via MFMA (M=16, N=128, 16 ksteps);
// per-graph fp32 atomic sums from bf16 LDS. Weights are bf16 n-major (prep).
// LDS ~40 KB -> 3 blocks/CU.
// ---------------------------------------------------------------------------
#define NPB 16   // 50000 % 16 == 0 -> 3125 blocks
#define XP  72   // xB stride  (64 + 8 pad), bf16
#define K1P 264  // 256-wide stride (+8), bf16
#define K2P 136  // 128-wide stride (+8), bf16

__global__ __launch_bounds__(256) void node_kernel(
    const float* __restrict__ x,
    const int* __restrict__ node_graph,
    const unsigned long long* __restrict__ inc1u, const unsigned long long* __restrict__ out1u,
    const unsigned long long* __restrict__ inc2u, const unsigned long long* __restrict__ out2u,
    const float* __restrict__ rcnt, const float* __restrict__ scnt,
    const __hip_bfloat16* __restrict__ Wn1t, const __hip_bfloat16* __restrict__ Win1t,
    const __hip_bfloat16* __restrict__ Wout1t, const float* __restrict__ bn1,
    const __hip_bfloat16* __restrict__ Wn2t, const __hip_bfloat16* __restrict__ Win2t,
    const __hip_bfloat16* __restrict__ Wout2t, const float* __restrict__ bn2,
    float* __restrict__ gn1, float* __restrict__ gn2, float* __restrict__ gncnt)
{
    __shared__ __hip_bfloat16 xB[NPB * XP];               // 2.25 KB
    __shared__ __hip_bfloat16 i1B[NPB * K1P];             // 8.25 KB
    __shared__ __hip_bfloat16 o1B[NPB * K1P];             // 8.25 KB
    __shared__ __hip_bfloat16 i2B[NPB * K2P];             // 4.25 KB
    __shared__ __hip_bfloat16 o2B[NPB * K2P];             // 4.25 KB
    __shared__ __hip_bfloat16 n1B[NPB * K1P];             // 8.25 KB
    __shared__ __hip_bfloat16 n2B[NPB * K2P];             // 4.25 KB
    __shared__ int gI[NPB];
    __shared__ float rrcp[NPB], srcp[NPB];

    const int t = threadIdx.x;
    const long n0 = (long)blockIdx.x * NPB;

    if (t < NPB) {
        gI[t] = node_graph[n0 + t];
        rrcp[t] = FXI16 / fmaxf(rcnt[n0 + t], 1.f);   // decode scale folded in
        srcp[t] = FXI16 / fmaxf(scnt[n0 + t], 1.f);
    }
    // x -> bf16 LDS (independent of rrcp)
    for (int i = t; i < NPB * 16; i += 256) {
        const int j = i >> 4, c4 = (i & 15) * 4;
        const float4 v = *(const float4*)&x[(n0 + j) * 64 + c4];
        *(__hip_bfloat162*)&xB[j * XP + c4]     = __float22bfloat162_rn(make_float2(v.x, v.y));
        *(__hip_bfloat162*)&xB[j * XP + c4 + 2] = __float22bfloat162_rn(make_float2(v.z, v.w));
    }
    __syncthreads();

    // decode u16x4 -> bf16 means
    for (int i = t; i < NPB * 64; i += 256) {
        const int j = i >> 6, w = i & 63;
        const size_t n = (size_t)(n0 + j);
        const unsigned long long av = inc1u[n * 64 + w];
        const unsigned long long bv = out1u[n * 64 + w];
        const float rr = rrcp[j], sr = srcp[j];
        const float2 a01 = make_float2((float)(unsigned int)(av & 0xFFFF) * rr,
                                       (float)(unsigned int)((av >> 16) & 0xFFFF) * rr);
        const float2 a23 = make_float2((float)(unsigned int)((av >> 32) & 0xFFFF) * rr,
                                       (float)(unsigned int)(av >> 48) * rr);
        const float2 b01 = make_float2((float)(unsigned int)(bv & 0xFFFF) * sr,
                                       (float)(unsigned int)((bv >> 16) & 0xFFFF) * sr);
        const float2 b23 = make_float2((float)(unsigned int)((bv >> 32) & 0xFFFF) * sr,
                                       (float)(unsigned int)(bv >> 48) * sr);
        *(__hip_bfloat162*)&i1B[j * K1P + 4 * w]     = __float22bfloat162_rn(a01);
        *(__hip_bfloat162*)&i1B[j * K1P + 4 * w + 2] = __float22bfloat162_rn(a23);
        *(__hip_bfloat162*)&o1B[j * K1P + 4 * w]     = __float22bfloat162_rn(b01);
        *(__hip_bfloat162*)&o1B[j * K1P + 4 * w + 2] = __float22bfloat162_rn(b23);
    }
    for (int i = t; i < NPB * 32; i += 256) {
        const int j = i >> 5, w = i & 31;
        const size_t n = (size_t)(n0 + j);
        const unsigned long long av = inc2u[n * 32 + w];
        const unsigned long long bv = out2u[n * 32 + w];
        const float rr = rrcp[j], sr = srcp[j];
        const float2 a01 = make_float2((float)(unsigned int)(av & 0xFFFF) * rr,
                                       (float)(unsigned int)((av >> 16) & 0xFFFF) * rr);
        const float2 a23 = make_float2((float)(unsigned int)((av >> 32) & 0xFFFF) * rr,
                                       (float)(unsigned int)(av >> 48) * rr);
        const float2 b01 = make_float2((float)(unsigned int)(bv & 0xFFFF) * sr,
                                       (float)(unsigned int)((bv >> 16) & 0xFFFF) * sr);
        const float2 b23 = make_float2((float)(unsigned int)((bv >> 32) & 0xFFFF) * sr,
                                       (float)(unsigned int)(bv >> 48) * sr);
        *(__hip_bfloat162*)&i2B[j * K2P + 4 * w]     = __float22bfloat162_rn(a01);
        *(__hip_bfloat162*)&i2B[j * K2P + 4 * w + 2] = __float22bfloat162_rn(a23);
        *(__hip_bfloat162*)&o2B[j * K2P + 4 * w]     = __float22bfloat162_rn(b01);
        *(__hip_bfloat162*)&o2B[j * K2P + 4 * w + 2] = __float22bfloat162_rn(b23);
    }
    __syncthreads();

    const int wv = t >> 6, ln = t & 63;
    const int r0 = ln & 15, q = ln >> 4;

    // ---- n1 MFMA: wave wv owns n-tiles 4wv..4wv+3 (N=256), M=16
    {
        f32x4 acc[4] = {{0.f,0.f,0.f,0.f},{0.f,0.f,0.f,0.f},
                        {0.f,0.f,0.f,0.f},{0.f,0.f,0.f,0.f}};
        // x @ Wn1 (K=64)
        #pragma unroll
        for (int ks = 0; ks < 2; ks++) {
            const int k0 = ks * 32 + q * 8;
            const bf16x8 a = *(const bf16x8*)&xB[r0 * XP + k0];
            #pragma unroll
            for (int nn = 0; nn < 4; nn++) {
                const int n = (wv * 4 + nn) * 16 + r0;
                const bf16x8 b = *(const bf16x8*)&Wn1t[(size_t)n * 64 + k0];
                acc[nn] = __builtin_amdgcn_mfma_f32_16x16x32_bf16(a, b, acc[nn], 0, 0, 0);
            }
        }
        // i1 @ Win1 (K=256)
        #pragma unroll
        for (int ks = 0; ks < 8; ks++) {
            const int k0 = ks * 32 + q * 8;
            const bf16x8 a = *(const bf16x8*)&i1B[r0 * K1P + k0];
            #pragma unroll
            for (int nn = 0; nn < 4; nn++) {
                const int n = (wv * 4 + nn) * 16 + r0;
                const bf16x8 b = *(const bf16x8*)&Win1t[(size_t)n * 256 + k0];
                acc[nn] = __builtin_amdgcn_mfma_f32_16x16x32_bf16(a, b, acc[nn], 0, 0, 0);
            }
        }
        // o1 @ Wout1 (K=256)
        #pragma unroll
        for (int ks = 0; ks < 8; ks++) {
            const int k0 = ks * 32 + q * 8;
            const bf16x8 a = *(const bf16x8*)&o1B[r0 * K1P + k0];
            #pragma unroll
            for (int nn = 0; nn < 4; nn++) {
                const int n = (wv * 4 + nn) * 16 + r0;
                const bf16x8 b = *(const bf16x8*)&Wout1t[(size_t)n * 256 + k0];
                acc[nn] = __builtin_amdgcn_mfma_f32_16x16x32_bf16(a, b, acc[nn], 0, 0, 0);
            }
        }
        // epilogue: D[m=q*4+r][n] -> bias+relu -> n1B bf16
        #pragma unroll
        for (int nn = 0; nn < 4; nn++) {
            const int n = (wv * 4 + nn) * 16 + r0;
            const float bz = bn1[n];
            #pragma unroll
            for (int r = 0; r < 4; r++) {
                const int m = q * 4 + r;
                n1B[m * K1P + n] = __float2bfloat16(fmaxf(acc[nn][r] + bz, 0.f));
            }
        }
    }
    __syncthreads();

    // ---- per-graph n1 sums (sorted-run aggregation)
    if (gI[0] == gI[NPB - 1]) {
        float s = 0.f;
        #pragma unroll
        for (int j = 0; j < NPB; j++) s += __bfloat162float(n1B[j * K1P + t]);
        atomicAdd(&gn1[(size_t)gI[0] * 256 + t], s);
        if (t == 0) atomicAdd(&gncnt[gI[0]], (float)NPB);
    } else {
        int j = 0;
        while (j < NPB) {
            const int g = gI[j];
            int j2 = j;
            float s = 0.f;
            while (j2 < NPB && gI[j2] == g) { s += __bfloat162float(n1B[j2 * K1P + t]); j2++; }
            atomicAdd(&gn1[(size_t)g * 256 + t], s);
            if (t == 0) atomicAdd(&gncnt[g], (float)(j2 - j));
            j = j2;
        }
    }

    // ---- n2 MFMA: wave wv owns n-tiles 2wv..2wv+1 (N=128), M=16
    {
        f32x4 acc[2] = {{0.f,0.f,0.f,0.f},{0.f,0.f,0.f,0.f}};
        // n1 @ Wn2 (K=256)
        #pragma unroll
        for (int ks = 0; ks < 8; ks++) {
            const int k0 = ks * 32 + q * 8;
            const bf16x8 a = *(const bf16x8*)&n1B[r0 * K1P + k0];
            #pragma unroll
            for (int nn = 0; nn < 2; nn++) {
                const int n = (wv * 2 + nn) * 16 + r0;
                const bf16x8 b = *(const bf16x8*)&Wn2t[(size_t)n * 256 + k0];
                acc[nn] = __builtin_amdgcn_mfma_f32_16x16x32_bf16(a, b, acc[nn], 0, 0, 0);
            }
        }
        // i2 @ Win2 (K=128)
        #pragma unroll
        for (int ks = 0; ks < 4; ks++) {
            const int k0 = ks * 32 + q * 8;
            const bf16x8 a = *(const bf16x8*)&i2B[r0 * K2P + k0];
            #pragma unroll
            for (int nn = 0; nn < 2; nn++) {
                const int n = (wv * 2 + nn) * 16 + r0;
                const bf16x8 b = *(const bf16x8*)&Win2t[(size_t)n * 128 + k0];
                acc[nn] = __builtin_amdgcn_mfma_f32_16x16x32_bf16(a, b, acc[nn], 0, 0, 0);
            }
        }
        // o2 @ Wout2 (K=128)
        #pragma unroll
        for (int ks = 0; ks < 4; ks++) {
            const int k0 = ks * 32 + q * 8;
            const bf16x8 a = *(const bf16x8*)&o2B[r0 * K2P + k0];
            #pragma unroll
            for (int nn = 0; nn < 2; nn++) {
                const int n = (wv * 2 + nn) * 16 + r0;
                const bf16x8 b = *(const bf16x8*)&Wout2t[(size_t)n * 128 + k0];
                acc[nn] = __builtin_amdgcn_mfma_f32_16x16x32_bf16(a, b, acc[nn], 0, 0, 0);
            }
        }
        #pragma unroll
        for (int nn = 0; nn < 2; nn++) {
            const int n = (wv * 2 + nn) * 16 + r0;
            const float bz = bn2[n];
            #pragma unroll
            for (int r = 0; r < 4; r++) {
                const int m = q * 4 + r;
                n2B[m * K2P + n] = __float2bfloat16(fmaxf(acc[nn][r] + bz, 0.f));
            }
        }
    }
    __syncthreads();

    // ---- per-graph n2 sums
    if (t < 128) {
        if (gI[0] == gI[NPB - 1]) {
            float s = 0.f;
            #pragma unroll
            for (int j = 0; j < NPB; j++) s += __bfloat162float(n2B[j * K2P + t]);
            atomicAdd(&gn2[(size_t)gI[0] * 128 + t], s);
        } else {
            int j = 0;
            while (j < NPB) {
                const int g = gI[j];
                int j2 = j;
                float s = 0.f;
                while (j2 < NPB && gI[j2] == g) { s += __bfloat162float(n2B[j2 * K2P + t]); j2++; }
                atomicAdd(&gn2[(size_t)g * 128 + t], s);
                j = j2;
            }
        }
    }
}

// ---------------------------------------------------------------------------
// Graph kernel: one block per graph. u1, u2, state_value, action MLP, output.
// ---------------------------------------------------------------------------
__global__ __launch_bounds__(256) void graph_kernel(
    const float* __restrict__ u,   // [B,64]
    const float* __restrict__ a,   // [B,8]
    const float* __restrict__ ge1, const float* __restrict__ ge2,
    const float* __restrict__ gecnt,
    const float* __restrict__ gn1, const float* __restrict__ gn2,
    const float* __restrict__ gncnt,
    const float* __restrict__ Wg1, const float* __restrict__ Wgn1,
    const float* __restrict__ Wge1, const float* __restrict__ bg1,
    const float* __restrict__ Wg2, const float* __restrict__ Wgn2,
    const float* __restrict__ Wge2, const float* __restrict__ bg2,
    const float* __restrict__ Wga, const float* __restrict__ bga,
    const float* __restrict__ Wa1, const float* __restrict__ ba1,
    const float* __restrict__ Wa2, const float* __restrict__ ba2,
    const float* __restrict__ Wa3, const float* __restrict__ ba3,
    float* __restrict__ out)
{
    const int g = blockIdx.x;
    const int t = threadIdx.x;
    __shared__ float uL[64], mn1[256], me1[256], mn2[128], me2[128];
    __shared__ float u1L[256], u2L[128], hL[144], h1L[256], h2L[256];
    __shared__ float red[4];

    const float ec = 1.f / fmaxf(gecnt[g], 1.f);
    const float nc = 1.f / fmaxf(gncnt[g], 1.f);
    if (t < 64) uL[t] = u[(size_t)g * 64 + t];
    mn1[t] = gn1[(size_t)g * 256 + t] * nc;
    me1[t] = ge1[(size_t)g * 256 + t] * ec;
    if (t < 128) {
        mn2[t] = gn2[(size_t)g * 128 + t] * nc;
        me2[t] = ge2[(size_t)g * 128 + t] * ec;
    }
    if (t >= 136 && t < 144) hL[t] = 0.f;
    __syncthreads();

    {
        float acc = bg1[t];
        for (int k = 0; k < 64; k++)  acc = fmaf(uL[k],  Wg1[(size_t)k * 256 + t], acc);
        for (int k = 0; k < 256; k++) acc = fmaf(mn1[k], Wgn1[(size_t)k * 256 + t], acc);
        for (int k = 0; k < 256; k++) acc = fmaf(me1[k], Wge1[(size_t)k * 256 + t], acc);
        u1L[t] = fmaxf(acc, 0.f);
    }
    __syncthreads();
    if (t < 128) {
        float acc = bg2[t];
        for (int k = 0; k < 256; k++) acc = fmaf(u1L[k], Wg2[(size_t)k * 128 + t], acc);
        for (int k = 0; k < 128; k++) acc = fmaf(mn2[k], Wgn2[(size_t)k * 128 + t], acc);
        for (int k = 0; k < 128; k++) acc = fmaf(me2[k], Wge2[(size_t)k * 128 + t], acc);
        u2L[t] = fmaxf(acc, 0.f);
    }
    __syncthreads();
    if (t < 128) {
        float acc = bga[t];
        for (int k = 0; k < 128; k++) acc = fmaf(u2L[k], Wga[(size_t)k * 128 + t], acc);
        hL[t] = acc;
    }
    if (t >= 128 && t < 136) hL[t] = a[(size_t)g * 8 + (t - 128)];
    __syncthreads();
    {
        float acc = ba1[t];
        for (int k = 0; k < 136; k++) acc = fmaf(hL[k], Wa1[(size_t)k * 256 + t], acc);
        h1L[t] = fmaxf(acc, 0.f);
    }
    __syncthreads();
    {
        float acc = ba2[t];
        for (int k = 0; k < 256; k++) acc = fmaf(h1L[k], Wa2[(size_t)k * 256 + t], acc);
        h2L[t] = fmaxf(acc, 0.f);
    }
    __syncthreads();
    {
        float p = h2L[t] * Wa3[t];
        for (int off = 32; off > 0; off >>= 1) p += __shfl_down(p, off, 64);
        if ((t & 63) == 0) red[t >> 6] = p;
        __syncthreads();
        if (t == 0) out[g] = red[0] + red[1] + red[2] + red[3] + ba3[0];
    }
}

// ---------------------------------------------------------------------------
extern "C" void kernel_launch(void* const* d_in, const int* in_sizes, int n_in,
                              void* d_out, int out_size, void* d_ws, size_t ws_size,
                              hipStream_t stream) {
    const float* x          = (const float*)d_in[0];
    const float* e          = (const float*)d_in[1];
    const float* u          = (const float*)d_in[2];
    const float* a          = (const float*)d_in[3];
    const int*   senders    = (const int*)d_in[4];
    const int*   receivers  = (const int*)d_in[5];
    const int*   node_graph = (const int*)d_in[6];
    const int*   edge_graph = (const int*)d_in[7];
    const float* We1 = (const float*)d_in[8];  const float* be1 = (const float*)d_in[9];
    const float* Wn1 = (const float*)d_in[10]; const float* Win1 = (const float*)d_in[11];
    const float* Wout1 = (const float*)d_in[12]; const float* bn1 = (const float*)d_in[13];
    const float* Wg1 = (const float*)d_in[14]; const float* Wgn1 = (const float*)d_in[15];
    const float* Wge1 = (const float*)d_in[16]; const float* bg1 = (const float*)d_in[17];
    const float* We2 = (const float*)d_in[18]; const float* be2 = (const float*)d_in[19];
    const float* Wn2 = (const float*)d_in[20]; const float* Win2 = (const float*)d_in[21];
    const float* Wout2 = (const float*)d_in[22]; const float* bn2 = (const float*)d_in[23];
    const float* Wg2 = (const float*)d_in[24]; const float* Wgn2 = (const float*)d_in[25];
    const float* Wge2 = (const float*)d_in[26]; const float* bg2 = (const float*)d_in[27];
    const float* Wga = (const float*)d_in[28]; const float* bga = (const float*)d_in[29];
    const float* Wa1 = (const float*)d_in[30]; const float* ba1 = (const float*)d_in[31];
    const float* Wa2 = (const float*)d_in[32]; const float* ba2 = (const float*)d_in[33];
    const float* Wa3 = (const float*)d_in[34]; const float* ba3 = (const float*)d_in[35];

    // u64 packed u16x4 accumulators (8B aligned), then fp32, then bf16 weights
    unsigned long long* uw = (unsigned long long*)d_ws;
    unsigned long long* inc1u = uw;                       uw += (size_t)N_NODES * 64;
    unsigned long long* out1u = uw;                       uw += (size_t)N_NODES * 64;
    unsigned long long* inc2u = uw;                       uw += (size_t)N_NODES * 32;
    unsigned long long* out2u = uw;                       uw += (size_t)N_NODES * 32;
    float* fw = (float*)uw;
    float* rcnt = fw;  fw += N_NODES;
    float* scnt = fw;  fw += N_NODES;
    float* ge1  = fw;  fw += (size_t)N_GRAPHS * 256;
    float* ge2  = fw;  fw += (size_t)N_GRAPHS * 128;
    float* gecnt = fw; fw += N_GRAPHS;
    float* gn1  = fw;  fw += (size_t)N_GRAPHS * 256;
    float* gn2  = fw;  fw += (size_t)N_GRAPHS * 128;
    float* gncnt = fw; fw += N_GRAPHS;
    const size_t total_bytes = (char*)fw - (char*)d_ws;
    __hip_bfloat16* bw = (__hip_bfloat16*)fw;   // 16B-aligned (see R9 notes)
    __hip_bfloat16* Wt2    = bw;  bw += 128 * 256;
    __hip_bfloat16* Wn1t   = bw;  bw += 256 * 64;
    __hip_bfloat16* Win1t  = bw;  bw += 256 * 256;
    __hip_bfloat16* Wout1t = bw;  bw += 256 * 256;
    __hip_bfloat16* Wn2t   = bw;  bw += 128 * 256;
    __hip_bfloat16* Win2t  = bw;  bw += 128 * 128;
    __hip_bfloat16* Wout2t = bw;  bw += 128 * 128;

    // zero accumulators (harness poisons d_ws with 0xAA before each call)
    hipMemsetAsync(d_ws, 0, total_bytes, stream);

    prep_kernel<<<960, 256, 0, stream>>>(
        We2, Wn1, Win1, Wout1, Wn2, Win2, Wout2,
        Wt2, Wn1t, Win1t, Wout1t, Wn2t, Win2t, Wout2t);

    edge_kernel<<<N_EDGES / EPB, 256, 0, stream>>>(
        e, senders, receivers, edge_graph, We1, be1, Wt2, be2,
        inc1u, out1u, inc2u, out2u, rcnt, scnt, ge1, ge2, gecnt);

    node_kernel<<<N_NODES / NPB, 256, 0, stream>>>(
        x, node_graph, inc1u, out1u, inc2u, out2u, rcnt, scnt,
        Wn1t, Win1t, Wout1t, bn1, Wn2t, Win2t, Wout2t, bn2, gn1, gn2, gncnt);

    graph_kernel<<<N_GRAPHS, 256, 0, stream>>>(
        u, a, ge1, ge2, gecnt, gn1, gn2, gncnt,
        Wg1, Wgn1, Wge1, bg1, Wg2, Wgn2, Wge2, bg2,
        Wga, bga, Wa1, ba1, Wa2, ba2, Wa3, ba3, (float*)d_out);
}